// Round 1
// baseline (1163.653 us; speedup 1.0000x reference)
//
#include <hip/hip_runtime.h>
#include <hip/hip_fp16.h>
#include <hip/hip_bf16.h>

// LightGCN propagation on MI355X (gfx950).
// out = (h0 + A*h0 + A^2*h0 + A^3*h0)/4, A = COO(edge_row, edge_col, edge_val)
//
// Round 4: scatter_kernel was random-64B-write bound (313 MB HBM writeback for a
// 40 MB payload: one full line evicted per 8B store, 7.8x amplification, 14% BW).
// Replace the per-row cursor scatter with a two-level scatter:
//   (a) bucket_scatter: bucket = 32 consecutive rows (9375 buckets). CSR region
//       of a bucket is [row_ptr[b*32], row_ptr[(b+1)*32]) -- contiguous, so a
//       per-bucket cursor gives ~9375 sequential write streams whose tail lines
//       stay cached and fill completely (plain stores for L2 merging).
//       row_local (5 bits) is packed into the low bits: word = val<<32|col<<5|rl.
//   (b) local_sort: one block per bucket; counting-sort the <=~600-edge segment
//       by row_local in LDS (cap 4096, global-scratch fallback for overflow),
//       write back in place. All traffic inside a 32 KB L2-resident window.
// SpMM unpack changes col = low32 >> 5 (1 VALU op per edge, free).

#define NUM_USERS 200000
#define NUM_ITEMS 100000
#define N_NODES   300000
#define EMB_DIM   64
#define NNZ       5000000

#define SCAN_TILE 1024
#define NTILES    ((N_NODES + SCAN_TILE - 1) / SCAN_TILE)   // 293

#define BUCKET_ROWS  32
#define NBUCKETS     (N_NODES / BUCKET_ROWS)                // 9375
#define SORT_CAP     4096                                   // mean 533, sd ~23

// ---------------------------------------------------------------------------
// init: out = ego (fp32), h = ego (fp16, 4 dims packed per uint2)
// ---------------------------------------------------------------------------
__global__ void init_kernel(const float4* __restrict__ user_emb,
                            const float4* __restrict__ item_emb,
                            uint2* __restrict__ h16,
                            float4* __restrict__ out) {
    const int n4 = N_NODES * (EMB_DIM / 4);
    int idx = blockIdx.x * blockDim.x + threadIdx.x;
    if (idx >= n4) return;
    const int user4 = NUM_USERS * (EMB_DIM / 4);
    float4 v = (idx < user4) ? user_emb[idx] : item_emb[idx - user4];
    out[idx] = v;
    __half2 p0 = __floats2half2_rn(v.x, v.y);
    __half2 p1 = __floats2half2_rn(v.z, v.w);
    uint2 u;
    u.x = *(unsigned int*)&p0;
    u.y = *(unsigned int*)&p1;
    h16[idx] = u;
}

// ---------------------------------------------------------------------------
// zero ints (counts / cursors)
// ---------------------------------------------------------------------------
__global__ void zero_int_kernel(int* __restrict__ p, int n) {
    int idx = blockIdx.x * blockDim.x + threadIdx.x;
    if (idx < n) p[idx] = 0;
}

// ---------------------------------------------------------------------------
// histogram of row indices
// ---------------------------------------------------------------------------
__global__ void hist_kernel(const int* __restrict__ row, int* __restrict__ counts) {
    int i = blockIdx.x * blockDim.x + threadIdx.x;
    if (i < NNZ) atomicAdd(&counts[row[i]], 1);
}

// ---------------------------------------------------------------------------
// scan phase 1: per-1024-tile sums
// ---------------------------------------------------------------------------
__global__ void scan_phase1(const int* __restrict__ counts, int* __restrict__ partials) {
    __shared__ int lds[256];
    int tile = blockIdx.x, t = threadIdx.x;
    int idx0 = tile * SCAN_TILE + t * 4;
    int s = 0;
#pragma unroll
    for (int i = 0; i < 4; ++i)
        if (idx0 + i < N_NODES) s += counts[idx0 + i];
    lds[t] = s;
    __syncthreads();
    for (int off = 128; off > 0; off >>= 1) {
        if (t < off) lds[t] += lds[t + off];
        __syncthreads();
    }
    if (t == 0) partials[tile] = lds[0];
}

// ---------------------------------------------------------------------------
// scan phase 2: single-block exclusive scan of tile sums
// ---------------------------------------------------------------------------
__global__ void scan_phase2(int* __restrict__ partials) {
    __shared__ int lds[512];
    int t = threadIdx.x;
    lds[t] = (t < NTILES) ? partials[t] : 0;
    __syncthreads();
    for (int off = 1; off < 512; off <<= 1) {
        int v = (t >= off) ? lds[t - off] : 0;
        __syncthreads();
        lds[t] += v;
        __syncthreads();
    }
    if (t < NTILES) partials[t] = (t > 0) ? lds[t - 1] : 0;  // exclusive
}

// ---------------------------------------------------------------------------
// scan phase 3: per-tile exclusive scan + tile offset -> row_ptr[0..N]
// ---------------------------------------------------------------------------
__global__ void scan_phase3(const int* __restrict__ counts,
                            const int* __restrict__ tile_excl,
                            int* __restrict__ row_ptr) {
    __shared__ int lds[256];
    int tile = blockIdx.x, t = threadIdx.x;
    int idx0 = tile * SCAN_TILE + t * 4;
    int c[4];
#pragma unroll
    for (int i = 0; i < 4; ++i)
        c[i] = (idx0 + i < N_NODES) ? counts[idx0 + i] : 0;
    int s = c[0] + c[1] + c[2] + c[3];
    lds[t] = s;
    __syncthreads();
    for (int off = 1; off < 256; off <<= 1) {
        int v = (t >= off) ? lds[t - off] : 0;
        __syncthreads();
        lds[t] += v;
        __syncthreads();
    }
    int thr_excl = (t > 0) ? lds[t - 1] : 0;
    int base = tile_excl[tile] + thr_excl;
    int run = 0;
#pragma unroll
    for (int i = 0; i < 4; ++i) {
        if (idx0 + i <= N_NODES) row_ptr[idx0 + i] = base + run;
        run += c[i];
    }
}

// ---------------------------------------------------------------------------
// bucket scatter: edge -> bucket region (32 rows/bucket). Sequential streams,
// plain stores so tail lines merge in L2. word = val<<32 | col<<5 | row_local.
// ---------------------------------------------------------------------------
__global__ void bucket_scatter(const int* __restrict__ row,
                               const int* __restrict__ col,
                               const float* __restrict__ val,
                               const int* __restrict__ row_ptr,
                               int* __restrict__ bcur,
                               unsigned long long* __restrict__ csr) {
    int i = blockIdx.x * blockDim.x + threadIdx.x;
    if (i >= NNZ) return;
    int r = row[i];
    int b = r >> 5;
    unsigned long long p = ((unsigned long long)__float_as_uint(val[i]) << 32)
                         | (unsigned long long)(((unsigned int)col[i] << 5)
                                              | (unsigned int)(r & 31));
    int base = row_ptr[b << 5];
    int pos  = base + atomicAdd(&bcur[b], 1);
    csr[pos] = p;
}

// ---------------------------------------------------------------------------
// per-bucket counting sort by row_local, in place. One block per bucket.
// Segment fits in a 32 KB window -> all traffic L2-local, full-line writebacks.
// ---------------------------------------------------------------------------
__global__ void local_sort(const int* __restrict__ row_ptr,
                           unsigned long long* __restrict__ csr,
                           unsigned long long* __restrict__ scratch) {
    __shared__ unsigned long long buf[SORT_CAP];
    __shared__ int cnt[BUCKET_ROWS];
    __shared__ int off[BUCKET_ROWS];
    __shared__ int cur[BUCKET_ROWS];
    int b  = blockIdx.x;
    int t  = threadIdx.x;
    int r0 = b << 5;
    int base = row_ptr[r0];
    int end  = row_ptr[r0 + BUCKET_ROWS];
    int n    = end - base;
    if (t < BUCKET_ROWS) { cnt[t] = 0; cur[t] = 0; }
    __syncthreads();
    if (n <= SORT_CAP) {
        for (int i = t; i < n; i += 256) {
            unsigned long long p = csr[base + i];
            buf[i] = p;
            atomicAdd(&cnt[(unsigned int)p & 31u], 1);
        }
        __syncthreads();
        if (t == 0) {
            int s = 0;
#pragma unroll
            for (int j = 0; j < BUCKET_ROWS; ++j) { off[j] = s; s += cnt[j]; }
        }
        __syncthreads();
        for (int i = t; i < n; i += 256) {
            unsigned long long p = buf[i];
            int rl  = (int)((unsigned int)p & 31u);
            int pos = off[rl] + atomicAdd(&cur[rl], 1);
            csr[base + pos] = p;   // scattered within 32 KB window (L2-resident)
        }
    } else {
        // overflow fallback (statistically unreachable): stage via global scratch.
        // Each thread re-reads only its own scratch slots -> no cross-thread dep.
        for (int i = t; i < n; i += 256) {
            unsigned long long p = csr[base + i];
            scratch[base + i] = p;
            atomicAdd(&cnt[(unsigned int)p & 31u], 1);
        }
        __syncthreads();
        if (t == 0) {
            int s = 0;
#pragma unroll
            for (int j = 0; j < BUCKET_ROWS; ++j) { off[j] = s; s += cnt[j]; }
        }
        __syncthreads();
        for (int i = t; i < n; i += 256) {
            unsigned long long p = scratch[base + i];
            int rl  = (int)((unsigned int)p & 31u);
            int pos = off[rl] + atomicAdd(&cur[rl], 1);
            csr[base + pos] = p;
        }
    }
}

// ---------------------------------------------------------------------------
// pull SpMM: one wave per row, lane = dim. fp16 gathers, fp32 accumulate.
// y16[r] = fp16(sum val*x[col]);  out = (out + sum) * scale   (fused)
// edge word: val<<32 | col<<5 | row_local  ->  col = low32 >> 5
// ---------------------------------------------------------------------------
__global__ void spmm_pull_kernel(const int* __restrict__ row_ptr,
                                 const unsigned long long* __restrict__ csr,
                                 const __half* __restrict__ x,
                                 __half* __restrict__ y,
                                 float* __restrict__ out,
                                 float scale) {
    int gid  = blockIdx.x * blockDim.x + threadIdx.x;
    int wid  = gid >> 6;
    int lane = threadIdx.x & 63;
    if (wid >= N_NODES) return;
    wid = __builtin_amdgcn_readfirstlane(wid);  // force SGPR: scalar edge loads
    int s = row_ptr[wid];
    int e = row_ptr[wid + 1];
    float acc = 0.f;
    int k = s;
    for (; k + 4 <= e; k += 4) {
        unsigned long long p0 = csr[k];
        unsigned long long p1 = csr[k + 1];
        unsigned long long p2 = csr[k + 2];
        unsigned long long p3 = csr[k + 3];
        unsigned int c0 = (unsigned int)p0 >> 5, c1 = (unsigned int)p1 >> 5;
        unsigned int c2 = (unsigned int)p2 >> 5, c3 = (unsigned int)p3 >> 5;
        float v0 = __uint_as_float((unsigned int)(p0 >> 32));
        float v1 = __uint_as_float((unsigned int)(p1 >> 32));
        float v2 = __uint_as_float((unsigned int)(p2 >> 32));
        float v3 = __uint_as_float((unsigned int)(p3 >> 32));
        float x0 = __half2float(x[(c0 << 6) + lane]);
        float x1 = __half2float(x[(c1 << 6) + lane]);
        float x2 = __half2float(x[(c2 << 6) + lane]);
        float x3 = __half2float(x[(c3 << 6) + lane]);
        acc += v0 * x0;
        acc += v1 * x1;
        acc += v2 * x2;
        acc += v3 * x3;
    }
    for (; k < e; ++k) {
        unsigned long long p = csr[k];
        unsigned int c = (unsigned int)p >> 5;
        float v = __uint_as_float((unsigned int)(p >> 32));
        acc += v * __half2float(x[(c << 6) + lane]);
    }
    int o = (wid << 6) + lane;
    y[o] = __float2half(acc);
    float prev = out[o];
    __builtin_nontemporal_store((prev + acc) * scale, &out[o]);
}

// ---------------------------------------------------------------------------
// fallback (round-1 push path) if ws too small
// ---------------------------------------------------------------------------
__global__ void init32_kernel(const float4* __restrict__ user_emb,
                              const float4* __restrict__ item_emb,
                              float4* __restrict__ h,
                              float4* __restrict__ out) {
    const int n4 = N_NODES * (EMB_DIM / 4);
    int idx = blockIdx.x * blockDim.x + threadIdx.x;
    if (idx >= n4) return;
    const int user4 = NUM_USERS * (EMB_DIM / 4);
    float4 v = (idx < user4) ? user_emb[idx] : item_emb[idx - user4];
    h[idx] = v;
    out[idx] = v;
}
__global__ void zero4_kernel(float4* __restrict__ p) {
    const int n4 = N_NODES * (EMB_DIM / 4);
    int idx = blockIdx.x * blockDim.x + threadIdx.x;
    if (idx < n4) p[idx] = make_float4(0.f, 0.f, 0.f, 0.f);
}
__global__ void spmm_push_kernel(const int* __restrict__ row, const int* __restrict__ col,
                                 const float* __restrict__ val, const float* __restrict__ x,
                                 float* __restrict__ y) {
    unsigned int gid = blockIdx.x * blockDim.x + threadIdx.x;
    unsigned int e = gid >> 6, lane = gid & 63u;
    if (e >= NNZ) return;
    atomicAdd(&y[(unsigned int)row[e] * EMB_DIM + lane],
              val[e] * x[(unsigned int)col[e] * EMB_DIM + lane]);
}
__global__ void acc_kernel(float4* __restrict__ out, const float4* __restrict__ h, float scale) {
    const int n4 = N_NODES * (EMB_DIM / 4);
    int idx = blockIdx.x * blockDim.x + threadIdx.x;
    if (idx >= n4) return;
    float4 o = out[idx], a = h[idx];
    o.x = (o.x + a.x) * scale; o.y = (o.y + a.y) * scale;
    o.z = (o.z + a.z) * scale; o.w = (o.w + a.w) * scale;
    out[idx] = o;
}

extern "C" void kernel_launch(void* const* d_in, const int* in_sizes, int n_in,
                              void* d_out, int out_size, void* d_ws, size_t ws_size,
                              hipStream_t stream) {
    const float* user_emb = (const float*)d_in[0];
    const float* item_emb = (const float*)d_in[1];
    const int*   edge_row = (const int*)d_in[2];
    const int*   edge_col = (const int*)d_in[3];
    const float* edge_val = (const float*)d_in[4];
    float* out = (float*)d_out;

    const size_t H16_BYTES = (size_t)N_NODES * EMB_DIM * sizeof(__half);  // 38.4 MB

    char* ws = (char*)d_ws;
    __half* hA     = (__half*)ws;                      ws += H16_BYTES;
    __half* hB     = (__half*)ws;                      ws += H16_BYTES;
    unsigned long long* csr = (unsigned long long*)ws; ws += (size_t)NNZ * 8;
    int*   row_ptr = (int*)ws;                         ws += (size_t)(N_NODES + 4) * 4;
    int*   counts  = (int*)ws;                         ws += (size_t)N_NODES * 4;
    int*   partials= (int*)ws;                         ws += 4096;
    const size_t REQUIRED = (size_t)(ws - (char*)d_ws);

    const int blk     = 256;
    const int n4      = N_NODES * (EMB_DIM / 4);
    const int grid_n4 = (n4 + blk - 1) / blk;
    const int grid_nz = (NNZ + blk - 1) / blk;
    const float scales[3] = {1.0f, 1.0f, 0.25f};

    if (ws_size >= REQUIRED) {
        // ---- build packed, row-sorted CSR (two-level scatter) ----
        zero_int_kernel<<<(N_NODES + blk - 1) / blk, blk, 0, stream>>>(counts, N_NODES);
        hist_kernel<<<grid_nz, blk, 0, stream>>>(edge_row, counts);
        scan_phase1<<<NTILES, 256, 0, stream>>>(counts, partials);
        scan_phase2<<<1, 512, 0, stream>>>(partials);
        scan_phase3<<<NTILES, 256, 0, stream>>>(counts, partials, row_ptr);
        zero_int_kernel<<<(NBUCKETS + blk - 1) / blk, blk, 0, stream>>>(counts, NBUCKETS);
        bucket_scatter<<<grid_nz, blk, 0, stream>>>(edge_row, edge_col, edge_val,
                                                    row_ptr, counts, csr);
        // hA/hB not yet written -> usable as overflow scratch (76.8 MB > 40 MB)
        local_sort<<<NBUCKETS, 256, 0, stream>>>(row_ptr, csr, (unsigned long long*)hA);
        // ---- propagate (fp16 h, fp32 out accumulation) ----
        init_kernel<<<grid_n4, blk, 0, stream>>>(
            (const float4*)user_emb, (const float4*)item_emb, (uint2*)hA, (float4*)out);
        __half* h = hA; __half* hn = hB;
        const int grid_sp = (int)(((long long)N_NODES * 64) / blk);  // 75,000
        for (int layer = 0; layer < 3; ++layer) {
            spmm_pull_kernel<<<grid_sp, blk, 0, stream>>>(
                row_ptr, csr, h, hn, out, scales[layer]);
            __half* t = h; h = hn; hn = t;
        }
    } else {
        // fallback: fp32 push path (needs only 2 * 76.8 MB)
        float* hA32 = (float*)d_ws;
        float* hB32 = hA32 + (size_t)N_NODES * EMB_DIM;
        init32_kernel<<<grid_n4, blk, 0, stream>>>(
            (const float4*)user_emb, (const float4*)item_emb, (float4*)hA32, (float4*)out);
        float* h = hA32; float* hn = hB32;
        const int grid_sp = (int)(((long long)NNZ * 64) / blk);
        for (int layer = 0; layer < 3; ++layer) {
            zero4_kernel<<<grid_n4, blk, 0, stream>>>((float4*)hn);
            spmm_push_kernel<<<grid_sp, blk, 0, stream>>>(edge_row, edge_col, edge_val, h, hn);
            acc_kernel<<<grid_n4, blk, 0, stream>>>((float4*)out, (const float4*)hn, scales[layer]);
            float* t = h; h = hn; hn = t;
        }
    }
}

// Round 2
// 966.575 us; speedup vs baseline: 1.2039x; 1.2039x over previous
//
#include <hip/hip_runtime.h>
#include <hip/hip_fp16.h>
#include <hip/hip_bf16.h>

// LightGCN propagation on MI355X (gfx950).
// out = (h0 + A*h0 + A^2*h0 + A^3*h0)/4, A = COO(edge_row, edge_col, edge_val)
//
// Round 5: bucket_scatter FAILED to reduce write amplification (WRITE_SIZE
// 303 MB, 60.6 B per 8B store). Cause: consecutive slots of a bucket are
// claimed by threads on DIFFERENT XCDs; the 8 non-coherent L2s each hold a
// partial dirty copy of the same line and evict it separately -> one ~64B
// HBM write per 8B store regardless of address sequentiality.
// Fix: radix-partition style scatter where every contiguous run is written by
// exactly ONE block (one XCD, one lifetime):
//   pass 1 (partition_coarse): 74 coarse bins (4096 rows). Block LDS-hists its
//     8192-edge chunk, reserves one contiguous run per bin via a single global
//     atomicAdd (run ~110 edges ~ 880B), scatters into its own runs. Fine-bin
//     id (row>>5)&127 stashed in free bits 24..31 of the packed word.
//   pass 2 (partition_fine): 9 blocks/coarse-bin, same reserve-then-scatter
//     into the 128 fine 32-row buckets (runs ~64 edges = 512B). Strips the
//     stashed bits -> word = val<<32 | col<<5 | row_local as before.
//   local_sort per 32-row bucket unchanged (counting sort by row_local).
// csr_tmp reuses hA/hB (free until init_kernel) -> no extra workspace.

#define NUM_USERS 200000
#define NUM_ITEMS 100000
#define N_NODES   300000
#define EMB_DIM   64
#define NNZ       5000000

#define SCAN_TILE 1024
#define NTILES    ((N_NODES + SCAN_TILE - 1) / SCAN_TILE)   // 293

#define BUCKET_ROWS  32
#define NBUCKETS     (N_NODES / BUCKET_ROWS)                // 9375
#define SORT_CAP     4096                                   // mean 533, sd ~23

#define COARSE_SHIFT 12
#define COARSE_ROWS  4096
#define NCOARSE      ((N_NODES + COARSE_ROWS - 1) / COARSE_ROWS)  // 74
#define FINE_PER_COARSE 128                                 // 4096/32

#define P1_CHUNK  8192
#define P1_BLOCKS ((NNZ + P1_CHUNK - 1) / P1_CHUNK)         // 611
#define P2_CHUNK  8192
#define P2_BPB    9                                         // 9*8192 > max region

// ---------------------------------------------------------------------------
// init: out = ego (fp32), h = ego (fp16, 4 dims packed per uint2)
// ---------------------------------------------------------------------------
__global__ void init_kernel(const float4* __restrict__ user_emb,
                            const float4* __restrict__ item_emb,
                            uint2* __restrict__ h16,
                            float4* __restrict__ out) {
    const int n4 = N_NODES * (EMB_DIM / 4);
    int idx = blockIdx.x * blockDim.x + threadIdx.x;
    if (idx >= n4) return;
    const int user4 = NUM_USERS * (EMB_DIM / 4);
    float4 v = (idx < user4) ? user_emb[idx] : item_emb[idx - user4];
    out[idx] = v;
    __half2 p0 = __floats2half2_rn(v.x, v.y);
    __half2 p1 = __floats2half2_rn(v.z, v.w);
    uint2 u;
    u.x = *(unsigned int*)&p0;
    u.y = *(unsigned int*)&p1;
    h16[idx] = u;
}

// ---------------------------------------------------------------------------
// zero ints (counts / cursors)
// ---------------------------------------------------------------------------
__global__ void zero_int_kernel(int* __restrict__ p, int n) {
    int idx = blockIdx.x * blockDim.x + threadIdx.x;
    if (idx < n) p[idx] = 0;
}

// ---------------------------------------------------------------------------
// histogram of row indices
// ---------------------------------------------------------------------------
__global__ void hist_kernel(const int* __restrict__ row, int* __restrict__ counts) {
    int i = blockIdx.x * blockDim.x + threadIdx.x;
    if (i < NNZ) atomicAdd(&counts[row[i]], 1);
}

// ---------------------------------------------------------------------------
// scan phase 1: per-1024-tile sums
// ---------------------------------------------------------------------------
__global__ void scan_phase1(const int* __restrict__ counts, int* __restrict__ partials) {
    __shared__ int lds[256];
    int tile = blockIdx.x, t = threadIdx.x;
    int idx0 = tile * SCAN_TILE + t * 4;
    int s = 0;
#pragma unroll
    for (int i = 0; i < 4; ++i)
        if (idx0 + i < N_NODES) s += counts[idx0 + i];
    lds[t] = s;
    __syncthreads();
    for (int off = 128; off > 0; off >>= 1) {
        if (t < off) lds[t] += lds[t + off];
        __syncthreads();
    }
    if (t == 0) partials[tile] = lds[0];
}

// ---------------------------------------------------------------------------
// scan phase 2: single-block exclusive scan of tile sums
// ---------------------------------------------------------------------------
__global__ void scan_phase2(int* __restrict__ partials) {
    __shared__ int lds[512];
    int t = threadIdx.x;
    lds[t] = (t < NTILES) ? partials[t] : 0;
    __syncthreads();
    for (int off = 1; off < 512; off <<= 1) {
        int v = (t >= off) ? lds[t - off] : 0;
        __syncthreads();
        lds[t] += v;
        __syncthreads();
    }
    if (t < NTILES) partials[t] = (t > 0) ? lds[t - 1] : 0;  // exclusive
}

// ---------------------------------------------------------------------------
// scan phase 3: per-tile exclusive scan + tile offset -> row_ptr[0..N]
// ---------------------------------------------------------------------------
__global__ void scan_phase3(const int* __restrict__ counts,
                            const int* __restrict__ tile_excl,
                            int* __restrict__ row_ptr) {
    __shared__ int lds[256];
    int tile = blockIdx.x, t = threadIdx.x;
    int idx0 = tile * SCAN_TILE + t * 4;
    int c[4];
#pragma unroll
    for (int i = 0; i < 4; ++i)
        c[i] = (idx0 + i < N_NODES) ? counts[idx0 + i] : 0;
    int s = c[0] + c[1] + c[2] + c[3];
    lds[t] = s;
    __syncthreads();
    for (int off = 1; off < 256; off <<= 1) {
        int v = (t >= off) ? lds[t - off] : 0;
        __syncthreads();
        lds[t] += v;
        __syncthreads();
    }
    int thr_excl = (t > 0) ? lds[t - 1] : 0;
    int base = tile_excl[tile] + thr_excl;
    int run = 0;
#pragma unroll
    for (int i = 0; i < 4; ++i) {
        if (idx0 + i <= N_NODES) row_ptr[idx0 + i] = base + run;
        run += c[i];
    }
}

// ---------------------------------------------------------------------------
// pass 1: partition edges into 74 coarse bins (4096 rows each).
// Per (block, bin): one global atomicAdd reserves a contiguous run; all stores
// of a run come from this block -> full-line writebacks from one XCD's L2.
// word = val<<32 | fine7<<24 | col<<5 | row_local5
// ---------------------------------------------------------------------------
__global__ void partition_coarse(const int* __restrict__ row,
                                 const int* __restrict__ col,
                                 const float* __restrict__ val,
                                 const int* __restrict__ row_ptr,
                                 int* __restrict__ ccur,
                                 unsigned long long* __restrict__ tmp) {
    __shared__ int hist[NCOARSE];
    __shared__ int lbase[NCOARSE];
    __shared__ int lcur[NCOARSE];
    int t = threadIdx.x;
    int start = blockIdx.x * P1_CHUNK;
    int end = min(start + P1_CHUNK, NNZ);
    for (int j = t; j < NCOARSE; j += 256) { hist[j] = 0; lcur[j] = 0; }
    __syncthreads();
    for (int i = start + t; i < end; i += 256)
        atomicAdd(&hist[(unsigned int)row[i] >> COARSE_SHIFT], 1);
    __syncthreads();
    for (int j = t; j < NCOARSE; j += 256) {
        int c = hist[j];
        if (c > 0)
            lbase[j] = row_ptr[j << COARSE_SHIFT] + atomicAdd(&ccur[j], c);
    }
    __syncthreads();
    for (int i = start + t; i < end; i += 256) {
        int r = row[i];
        int b = (int)((unsigned int)r >> COARSE_SHIFT);
        unsigned int fine7 = ((unsigned int)r >> 5) & 127u;
        unsigned int lo = (fine7 << 24) | ((unsigned int)col[i] << 5)
                        | ((unsigned int)r & 31u);
        unsigned long long p = ((unsigned long long)__float_as_uint(val[i]) << 32)
                             | (unsigned long long)lo;
        int pos = lbase[b] + atomicAdd(&lcur[b], 1);
        tmp[pos] = p;
    }
}

// ---------------------------------------------------------------------------
// pass 2: partition each coarse region into its 128 fine 32-row buckets.
// 9 blocks per coarse bin, grid-stride over the region for safety.
// Strips fine7 -> word = val<<32 | col<<5 | row_local (spmm format).
// ---------------------------------------------------------------------------
__global__ void partition_fine(const int* __restrict__ row_ptr,
                               const unsigned long long* __restrict__ tmp,
                               int* __restrict__ fcur,
                               unsigned long long* __restrict__ csr) {
    __shared__ int hist[FINE_PER_COARSE];
    __shared__ int lbase[FINE_PER_COARSE];
    __shared__ int lcur[FINE_PER_COARSE];
    __shared__ int fbase[FINE_PER_COARSE];
    int t = threadIdx.x;
    int bin = blockIdx.x / P2_BPB;
    int sub = blockIdx.x % P2_BPB;
    int rstart = row_ptr[bin << COARSE_SHIFT];
    int rend   = row_ptr[min((bin + 1) << COARSE_SHIFT, N_NODES)];
    if (t < FINE_PER_COARSE) {
        int r0 = ((bin << 7) | t) << 5;
        fbase[t] = (r0 < N_NODES) ? row_ptr[r0] : 0;
    }
    for (int cstart = rstart + sub * P2_CHUNK; cstart < rend;
         cstart += P2_BPB * P2_CHUNK) {
        int cend = min(cstart + P2_CHUNK, rend);
        if (t < FINE_PER_COARSE) { hist[t] = 0; lcur[t] = 0; }
        __syncthreads();
        for (int i = cstart + t; i < cend; i += 256)
            atomicAdd(&hist[((unsigned int)tmp[i] >> 24) & 127u], 1);
        __syncthreads();
        if (t < FINE_PER_COARSE) {
            int c = hist[t];
            if (c > 0)
                lbase[t] = fbase[t] + atomicAdd(&fcur[(bin << 7) | t], c);
        }
        __syncthreads();
        for (int i = cstart + t; i < cend; i += 256) {
            unsigned long long p = tmp[i];
            int f = (int)(((unsigned int)p >> 24) & 127u);
            int pos = lbase[f] + atomicAdd(&lcur[f], 1);
            csr[pos] = p & 0xFFFFFFFF00FFFFFFull;   // strip fine7
        }
        __syncthreads();
    }
}

// ---------------------------------------------------------------------------
// per-bucket counting sort by row_local, in place. One block per bucket.
// Segment fits in a 32 KB window -> all traffic L2-local, full-line writebacks.
// ---------------------------------------------------------------------------
__global__ void local_sort(const int* __restrict__ row_ptr,
                           unsigned long long* __restrict__ csr,
                           unsigned long long* __restrict__ scratch) {
    __shared__ unsigned long long buf[SORT_CAP];
    __shared__ int cnt[BUCKET_ROWS];
    __shared__ int off[BUCKET_ROWS];
    __shared__ int cur[BUCKET_ROWS];
    int b  = blockIdx.x;
    int t  = threadIdx.x;
    int r0 = b << 5;
    int base = row_ptr[r0];
    int end  = row_ptr[r0 + BUCKET_ROWS];
    int n    = end - base;
    if (t < BUCKET_ROWS) { cnt[t] = 0; cur[t] = 0; }
    __syncthreads();
    if (n <= SORT_CAP) {
        for (int i = t; i < n; i += 256) {
            unsigned long long p = csr[base + i];
            buf[i] = p;
            atomicAdd(&cnt[(unsigned int)p & 31u], 1);
        }
        __syncthreads();
        if (t == 0) {
            int s = 0;
#pragma unroll
            for (int j = 0; j < BUCKET_ROWS; ++j) { off[j] = s; s += cnt[j]; }
        }
        __syncthreads();
        for (int i = t; i < n; i += 256) {
            unsigned long long p = buf[i];
            int rl  = (int)((unsigned int)p & 31u);
            int pos = off[rl] + atomicAdd(&cur[rl], 1);
            csr[base + pos] = p;   // scattered within 32 KB window (L2-resident)
        }
    } else {
        // overflow fallback (statistically unreachable): stage via global scratch.
        for (int i = t; i < n; i += 256) {
            unsigned long long p = csr[base + i];
            scratch[base + i] = p;
            atomicAdd(&cnt[(unsigned int)p & 31u], 1);
        }
        __syncthreads();
        if (t == 0) {
            int s = 0;
#pragma unroll
            for (int j = 0; j < BUCKET_ROWS; ++j) { off[j] = s; s += cnt[j]; }
        }
        __syncthreads();
        for (int i = t; i < n; i += 256) {
            unsigned long long p = scratch[base + i];
            int rl  = (int)((unsigned int)p & 31u);
            int pos = off[rl] + atomicAdd(&cur[rl], 1);
            csr[base + pos] = p;
        }
    }
}

// ---------------------------------------------------------------------------
// pull SpMM: one wave per row, lane = dim. fp16 gathers, fp32 accumulate.
// y16[r] = fp16(sum val*x[col]);  out = (out + sum) * scale   (fused)
// edge word: val<<32 | col<<5 | row_local  ->  col = low32 >> 5
// ---------------------------------------------------------------------------
__global__ void spmm_pull_kernel(const int* __restrict__ row_ptr,
                                 const unsigned long long* __restrict__ csr,
                                 const __half* __restrict__ x,
                                 __half* __restrict__ y,
                                 float* __restrict__ out,
                                 float scale) {
    int gid  = blockIdx.x * blockDim.x + threadIdx.x;
    int wid  = gid >> 6;
    int lane = threadIdx.x & 63;
    if (wid >= N_NODES) return;
    wid = __builtin_amdgcn_readfirstlane(wid);  // force SGPR: scalar edge loads
    int s = row_ptr[wid];
    int e = row_ptr[wid + 1];
    float acc = 0.f;
    int k = s;
    for (; k + 4 <= e; k += 4) {
        unsigned long long p0 = csr[k];
        unsigned long long p1 = csr[k + 1];
        unsigned long long p2 = csr[k + 2];
        unsigned long long p3 = csr[k + 3];
        unsigned int c0 = (unsigned int)p0 >> 5, c1 = (unsigned int)p1 >> 5;
        unsigned int c2 = (unsigned int)p2 >> 5, c3 = (unsigned int)p3 >> 5;
        float v0 = __uint_as_float((unsigned int)(p0 >> 32));
        float v1 = __uint_as_float((unsigned int)(p1 >> 32));
        float v2 = __uint_as_float((unsigned int)(p2 >> 32));
        float v3 = __uint_as_float((unsigned int)(p3 >> 32));
        float x0 = __half2float(x[(c0 << 6) + lane]);
        float x1 = __half2float(x[(c1 << 6) + lane]);
        float x2 = __half2float(x[(c2 << 6) + lane]);
        float x3 = __half2float(x[(c3 << 6) + lane]);
        acc += v0 * x0;
        acc += v1 * x1;
        acc += v2 * x2;
        acc += v3 * x3;
    }
    for (; k < e; ++k) {
        unsigned long long p = csr[k];
        unsigned int c = (unsigned int)p >> 5;
        float v = __uint_as_float((unsigned int)(p >> 32));
        acc += v * __half2float(x[(c << 6) + lane]);
    }
    int o = (wid << 6) + lane;
    y[o] = __float2half(acc);
    float prev = out[o];
    __builtin_nontemporal_store((prev + acc) * scale, &out[o]);
}

// ---------------------------------------------------------------------------
// fallback (round-1 push path) if ws too small
// ---------------------------------------------------------------------------
__global__ void init32_kernel(const float4* __restrict__ user_emb,
                              const float4* __restrict__ item_emb,
                              float4* __restrict__ h,
                              float4* __restrict__ out) {
    const int n4 = N_NODES * (EMB_DIM / 4);
    int idx = blockIdx.x * blockDim.x + threadIdx.x;
    if (idx >= n4) return;
    const int user4 = NUM_USERS * (EMB_DIM / 4);
    float4 v = (idx < user4) ? user_emb[idx] : item_emb[idx - user4];
    h[idx] = v;
    out[idx] = v;
}
__global__ void zero4_kernel(float4* __restrict__ p) {
    const int n4 = N_NODES * (EMB_DIM / 4);
    int idx = blockIdx.x * blockDim.x + threadIdx.x;
    if (idx < n4) p[idx] = make_float4(0.f, 0.f, 0.f, 0.f);
}
__global__ void spmm_push_kernel(const int* __restrict__ row, const int* __restrict__ col,
                                 const float* __restrict__ val, const float* __restrict__ x,
                                 float* __restrict__ y) {
    unsigned int gid = blockIdx.x * blockDim.x + threadIdx.x;
    unsigned int e = gid >> 6, lane = gid & 63u;
    if (e >= NNZ) return;
    atomicAdd(&y[(unsigned int)row[e] * EMB_DIM + lane],
              val[e] * x[(unsigned int)col[e] * EMB_DIM + lane]);
}
__global__ void acc_kernel(float4* __restrict__ out, const float4* __restrict__ h, float scale) {
    const int n4 = N_NODES * (EMB_DIM / 4);
    int idx = blockIdx.x * blockDim.x + threadIdx.x;
    if (idx >= n4) return;
    float4 o = out[idx], a = h[idx];
    o.x = (o.x + a.x) * scale; o.y = (o.y + a.y) * scale;
    o.z = (o.z + a.z) * scale; o.w = (o.w + a.w) * scale;
    out[idx] = o;
}

extern "C" void kernel_launch(void* const* d_in, const int* in_sizes, int n_in,
                              void* d_out, int out_size, void* d_ws, size_t ws_size,
                              hipStream_t stream) {
    const float* user_emb = (const float*)d_in[0];
    const float* item_emb = (const float*)d_in[1];
    const int*   edge_row = (const int*)d_in[2];
    const int*   edge_col = (const int*)d_in[3];
    const float* edge_val = (const float*)d_in[4];
    float* out = (float*)d_out;

    const size_t H16_BYTES = (size_t)N_NODES * EMB_DIM * sizeof(__half);  // 38.4 MB

    char* ws = (char*)d_ws;
    __half* hA     = (__half*)ws;                      ws += H16_BYTES;
    __half* hB     = (__half*)ws;                      ws += H16_BYTES;
    unsigned long long* csr = (unsigned long long*)ws; ws += (size_t)NNZ * 8;
    int*   row_ptr = (int*)ws;                         ws += (size_t)(N_NODES + 4) * 4;
    int*   counts  = (int*)ws;                         ws += (size_t)N_NODES * 4;
    int*   partials= (int*)ws;                         ws += 4096;
    const size_t REQUIRED = (size_t)(ws - (char*)d_ws);

    const int blk     = 256;
    const int n4      = N_NODES * (EMB_DIM / 4);
    const int grid_n4 = (n4 + blk - 1) / blk;
    const int grid_nz = (NNZ + blk - 1) / blk;
    const float scales[3] = {1.0f, 1.0f, 0.25f};

    if (ws_size >= REQUIRED) {
        // ---- build packed, row-sorted CSR (coarse->fine partition + sort) ----
        zero_int_kernel<<<(N_NODES + blk - 1) / blk, blk, 0, stream>>>(counts, N_NODES);
        hist_kernel<<<grid_nz, blk, 0, stream>>>(edge_row, counts);
        scan_phase1<<<NTILES, 256, 0, stream>>>(counts, partials);
        scan_phase2<<<1, 512, 0, stream>>>(partials);
        scan_phase3<<<NTILES, 256, 0, stream>>>(counts, partials, row_ptr);
        // cursors: fine in counts[0..NBUCKETS), coarse in partials[0..NCOARSE)
        zero_int_kernel<<<(NBUCKETS + blk - 1) / blk, blk, 0, stream>>>(counts, NBUCKETS);
        zero_int_kernel<<<1, 128, 0, stream>>>(partials, NCOARSE);
        // csr_tmp reuses hA/hB region (76.8 MB >= 40 MB), dead before init.
        unsigned long long* csr_tmp = (unsigned long long*)hA;
        partition_coarse<<<P1_BLOCKS, 256, 0, stream>>>(
            edge_row, edge_col, edge_val, row_ptr, partials, csr_tmp);
        partition_fine<<<NCOARSE * P2_BPB, 256, 0, stream>>>(
            row_ptr, csr_tmp, counts, csr);
        local_sort<<<NBUCKETS, 256, 0, stream>>>(row_ptr, csr, csr_tmp);
        // ---- propagate (fp16 h, fp32 out accumulation) ----
        init_kernel<<<grid_n4, blk, 0, stream>>>(
            (const float4*)user_emb, (const float4*)item_emb, (uint2*)hA, (float4*)out);
        __half* h = hA; __half* hn = hB;
        const int grid_sp = (int)(((long long)N_NODES * 64) / blk);  // 75,000
        for (int layer = 0; layer < 3; ++layer) {
            spmm_pull_kernel<<<grid_sp, blk, 0, stream>>>(
                row_ptr, csr, h, hn, out, scales[layer]);
            __half* t = h; h = hn; hn = t;
        }
    } else {
        // fallback: fp32 push path (needs only 2 * 76.8 MB)
        float* hA32 = (float*)d_ws;
        float* hB32 = hA32 + (size_t)N_NODES * EMB_DIM;
        init32_kernel<<<grid_n4, blk, 0, stream>>>(
            (const float4*)user_emb, (const float4*)item_emb, (float4*)hA32, (float4*)out);
        float* h = hA32; float* hn = hB32;
        const int grid_sp = (int)(((long long)NNZ * 64) / blk);
        for (int layer = 0; layer < 3; ++layer) {
            zero4_kernel<<<grid_n4, blk, 0, stream>>>((float4*)hn);
            spmm_push_kernel<<<grid_sp, blk, 0, stream>>>(edge_row, edge_col, edge_val, h, hn);
            acc_kernel<<<grid_n4, blk, 0, stream>>>((float4*)out, (const float4*)hn, scales[layer]);
            float* t = h; h = hn; hn = t;
        }
    }
}

// Round 4
// 835.307 us; speedup vs baseline: 1.3931x; 1.1571x over previous
//
#include <hip/hip_runtime.h>
#include <hip/hip_fp16.h>
#include <hip/hip_bf16.h>

// LightGCN propagation on MI355X (gfx950).
// out = (h0 + A*h0 + A^2*h0 + A^3*h0)/4, A = COO(edge_row, edge_col, edge_val)
//
// Round 7 = round 6 resubmit (container infra failure, no kernel verdict).
// Round 6 design: hist_kernel (global atomicAdd on 300K counters) was 189 us
// with 156 MB WRITE_SIZE -- every device-scope atomic on a random line is a
// ~32B HBM-side RMW (8 non-coherent L2s force atomics to the memory side).
// Replace the whole row_ptr/scatter pipeline with:
//   1. coarse_hist: LDS-private 293-bin histogram (1024 rows/bin), one global
//      atomicAdd per (block,bin) -> ~90K atomics instead of 5M.
//   2. coarse_scan: exclusive scan of 293 coarse counts (1 block).
//   3. partition_coarse: per-(block,bin) contiguous run reservation, scatter
//      into coarse regions of tmp (one XCD owns each run -> full-line
//      writebacks). word = val<<32 | col<<10 | row_local10.
//   4. fine_scatter: one block per coarse bin. LDS 1024-bin histogram of its
//      region (no global atomics), block scan -> row_ptr for its 1024 rows,
//      then scatter region into final row-sorted CSR via LDS cursors. All
//      writes block-private within a ~137 KB L2-resident window.
// This removes hist_kernel, scan_phase1/2/3, partition_fine, local_sort.
// spmm unpacks col = lo >> 10 (row bits unused there).

#define NUM_USERS 200000
#define NUM_ITEMS 100000
#define N_NODES   300000
#define EMB_DIM   64
#define NNZ       5000000

#define COARSE_SHIFT 10
#define COARSE_ROWS  1024
#define NCOARSE      ((N_NODES + COARSE_ROWS - 1) / COARSE_ROWS)  // 293

#define P1_CHUNK  16384
#define P1_BLOCKS ((NNZ + P1_CHUNK - 1) / P1_CHUNK)               // 306

// ---------------------------------------------------------------------------
// init: out = ego (fp32), h = ego (fp16, 4 dims packed per uint2)
// ---------------------------------------------------------------------------
__global__ void init_kernel(const float4* __restrict__ user_emb,
                            const float4* __restrict__ item_emb,
                            uint2* __restrict__ h16,
                            float4* __restrict__ out) {
    const int n4 = N_NODES * (EMB_DIM / 4);
    int idx = blockIdx.x * blockDim.x + threadIdx.x;
    if (idx >= n4) return;
    const int user4 = NUM_USERS * (EMB_DIM / 4);
    float4 v = (idx < user4) ? user_emb[idx] : item_emb[idx - user4];
    out[idx] = v;
    __half2 p0 = __floats2half2_rn(v.x, v.y);
    __half2 p1 = __floats2half2_rn(v.z, v.w);
    uint2 u;
    u.x = *(unsigned int*)&p0;
    u.y = *(unsigned int*)&p1;
    h16[idx] = u;
}

// ---------------------------------------------------------------------------
// zero ints (counts / cursors)
// ---------------------------------------------------------------------------
__global__ void zero_int_kernel(int* __restrict__ p, int n) {
    int idx = blockIdx.x * blockDim.x + threadIdx.x;
    if (idx < n) p[idx] = 0;
}

// ---------------------------------------------------------------------------
// coarse histogram: LDS-privatized 293 bins, one global atomic per (block,bin)
// ---------------------------------------------------------------------------
__global__ void coarse_hist(const int* __restrict__ row, int* __restrict__ ccnt) {
    __shared__ int h[NCOARSE];
    int t = threadIdx.x;
    for (int j = t; j < NCOARSE; j += 256) h[j] = 0;
    __syncthreads();
    int start = blockIdx.x * P1_CHUNK;
    int end = min(start + P1_CHUNK, NNZ);
    for (int i = start + t; i < end; i += 256)
        atomicAdd(&h[(unsigned int)row[i] >> COARSE_SHIFT], 1);
    __syncthreads();
    for (int j = t; j < NCOARSE; j += 256)
        if (h[j] > 0) atomicAdd(&ccnt[j], h[j]);
}

// ---------------------------------------------------------------------------
// exclusive scan of 293 coarse counts -> cbase[0..293] (cbase[293] = NNZ)
// ---------------------------------------------------------------------------
__global__ void coarse_scan(int* __restrict__ p) {
    __shared__ int lds[512];
    int t = threadIdx.x;
    lds[t] = (t < NCOARSE) ? p[t] : 0;
    __syncthreads();
    for (int off = 1; off < 512; off <<= 1) {
        int v = (t >= off) ? lds[t - off] : 0;
        __syncthreads();
        lds[t] += v;
        __syncthreads();
    }
    if (t < NCOARSE) p[t] = (t > 0) ? lds[t - 1] : 0;
    if (t == 0) p[NCOARSE] = lds[NCOARSE - 1];
}

// ---------------------------------------------------------------------------
// pass 1: partition edges into 293 coarse bins (1024 rows each).
// Per (block, bin): one global atomicAdd reserves a contiguous run; all stores
// of a run come from this block -> full-line writebacks from one XCD's L2.
// word = val<<32 | col<<10 | row_local10
// ---------------------------------------------------------------------------
__global__ void partition_coarse(const int* __restrict__ row,
                                 const int* __restrict__ col,
                                 const float* __restrict__ val,
                                 const int* __restrict__ cbase,
                                 int* __restrict__ ccur,
                                 unsigned long long* __restrict__ tmp) {
    __shared__ int hist[NCOARSE];
    __shared__ int lbase[NCOARSE];
    __shared__ int lcur[NCOARSE];
    int t = threadIdx.x;
    int start = blockIdx.x * P1_CHUNK;
    int end = min(start + P1_CHUNK, NNZ);
    for (int j = t; j < NCOARSE; j += 256) { hist[j] = 0; lcur[j] = 0; }
    __syncthreads();
    for (int i = start + t; i < end; i += 256)
        atomicAdd(&hist[(unsigned int)row[i] >> COARSE_SHIFT], 1);
    __syncthreads();
    for (int j = t; j < NCOARSE; j += 256) {
        int c = hist[j];
        if (c > 0)
            lbase[j] = cbase[j] + atomicAdd(&ccur[j], c);
    }
    __syncthreads();
    for (int i = start + t; i < end; i += 256) {
        int r = row[i];
        int b = (int)((unsigned int)r >> COARSE_SHIFT);
        unsigned int lo = ((unsigned int)col[i] << 10) | ((unsigned int)r & 1023u);
        unsigned long long p = ((unsigned long long)__float_as_uint(val[i]) << 32)
                             | (unsigned long long)lo;
        int pos = lbase[b] + atomicAdd(&lcur[b], 1);
        tmp[pos] = p;
    }
}

// ---------------------------------------------------------------------------
// pass 2: one block per coarse bin. LDS histogram of the bin's region by
// row_local (no global atomics), block scan -> row_ptr for its 1024 rows,
// then scatter the region into final row-sorted CSR positions via LDS
// cursors. All traffic inside a ~137 KB L2-resident window, block-private.
// ---------------------------------------------------------------------------
__global__ void __launch_bounds__(1024)
fine_scatter(const int* __restrict__ cbase,
             const unsigned long long* __restrict__ tmp,
             unsigned long long* __restrict__ csr,
             int* __restrict__ row_ptr) {
    __shared__ int offs[COARSE_ROWS];
    __shared__ int cur[COARSE_ROWS];
    int t = threadIdx.x;
    int bin = blockIdx.x;
    int cstart = cbase[bin];
    int cend   = cbase[bin + 1];
    offs[t] = 0;
    cur[t] = 0;
    __syncthreads();
    for (int i = cstart + t; i < cend; i += 1024)
        atomicAdd(&offs[(unsigned int)tmp[i] & 1023u], 1);
    __syncthreads();
    int c = offs[t];
    // inclusive scan in place (Hillis-Steele)
    for (int off = 1; off < 1024; off <<= 1) {
        int v = (t >= off) ? offs[t - off] : 0;
        __syncthreads();
        offs[t] += v;
        __syncthreads();
    }
    int excl = offs[t] - c;
    __syncthreads();
    offs[t] = excl;      // offs[] now holds exclusive per-row offsets
    __syncthreads();
    int r = (bin << COARSE_SHIFT) + t;
    if (r < N_NODES) row_ptr[r] = cstart + excl;
    if (bin == NCOARSE - 1 && t == 0) row_ptr[N_NODES] = cend;
    for (int i = cstart + t; i < cend; i += 1024) {
        unsigned long long p = tmp[i];
        int rl = (int)((unsigned int)p & 1023u);
        int pos = cstart + offs[rl] + atomicAdd(&cur[rl], 1);
        csr[pos] = p;    // scattered within ~137 KB window (L2-resident)
    }
}

// ---------------------------------------------------------------------------
// pull SpMM: one wave per row, lane = dim. fp16 gathers, fp32 accumulate.
// y16[r] = fp16(sum val*x[col]);  out = (out + sum) * scale   (fused)
// edge word: val<<32 | col<<10 | row_local10  ->  col = low32 >> 10
// ---------------------------------------------------------------------------
__global__ void spmm_pull_kernel(const int* __restrict__ row_ptr,
                                 const unsigned long long* __restrict__ csr,
                                 const __half* __restrict__ x,
                                 __half* __restrict__ y,
                                 float* __restrict__ out,
                                 float scale) {
    int gid  = blockIdx.x * blockDim.x + threadIdx.x;
    int wid  = gid >> 6;
    int lane = threadIdx.x & 63;
    if (wid >= N_NODES) return;
    wid = __builtin_amdgcn_readfirstlane(wid);  // force SGPR: scalar edge loads
    int s = row_ptr[wid];
    int e = row_ptr[wid + 1];
    float acc = 0.f;
    int k = s;
    for (; k + 4 <= e; k += 4) {
        unsigned long long p0 = csr[k];
        unsigned long long p1 = csr[k + 1];
        unsigned long long p2 = csr[k + 2];
        unsigned long long p3 = csr[k + 3];
        unsigned int c0 = (unsigned int)p0 >> 10, c1 = (unsigned int)p1 >> 10;
        unsigned int c2 = (unsigned int)p2 >> 10, c3 = (unsigned int)p3 >> 10;
        float v0 = __uint_as_float((unsigned int)(p0 >> 32));
        float v1 = __uint_as_float((unsigned int)(p1 >> 32));
        float v2 = __uint_as_float((unsigned int)(p2 >> 32));
        float v3 = __uint_as_float((unsigned int)(p3 >> 32));
        float x0 = __half2float(x[(c0 << 6) + lane]);
        float x1 = __half2float(x[(c1 << 6) + lane]);
        float x2 = __half2float(x[(c2 << 6) + lane]);
        float x3 = __half2float(x[(c3 << 6) + lane]);
        acc += v0 * x0;
        acc += v1 * x1;
        acc += v2 * x2;
        acc += v3 * x3;
    }
    for (; k < e; ++k) {
        unsigned long long p = csr[k];
        unsigned int c = (unsigned int)p >> 10;
        float v = __uint_as_float((unsigned int)(p >> 32));
        acc += v * __half2float(x[(c << 6) + lane]);
    }
    int o = (wid << 6) + lane;
    y[o] = __float2half(acc);
    float prev = out[o];
    __builtin_nontemporal_store((prev + acc) * scale, &out[o]);
}

// ---------------------------------------------------------------------------
// fallback (round-1 push path) if ws too small
// ---------------------------------------------------------------------------
__global__ void init32_kernel(const float4* __restrict__ user_emb,
                              const float4* __restrict__ item_emb,
                              float4* __restrict__ h,
                              float4* __restrict__ out) {
    const int n4 = N_NODES * (EMB_DIM / 4);
    int idx = blockIdx.x * blockDim.x + threadIdx.x;
    if (idx >= n4) return;
    const int user4 = NUM_USERS * (EMB_DIM / 4);
    float4 v = (idx < user4) ? user_emb[idx] : item_emb[idx - user4];
    h[idx] = v;
    out[idx] = v;
}
__global__ void zero4_kernel(float4* __restrict__ p) {
    const int n4 = N_NODES * (EMB_DIM / 4);
    int idx = blockIdx.x * blockDim.x + threadIdx.x;
    if (idx < n4) p[idx] = make_float4(0.f, 0.f, 0.f, 0.f);
}
__global__ void spmm_push_kernel(const int* __restrict__ row, const int* __restrict__ col,
                                 const float* __restrict__ val, const float* __restrict__ x,
                                 float* __restrict__ y) {
    unsigned int gid = blockIdx.x * blockDim.x + threadIdx.x;
    unsigned int e = gid >> 6, lane = gid & 63u;
    if (e >= NNZ) return;
    atomicAdd(&y[(unsigned int)row[e] * EMB_DIM + lane],
              val[e] * x[(unsigned int)col[e] * EMB_DIM + lane]);
}
__global__ void acc_kernel(float4* __restrict__ out, const float4* __restrict__ h, float scale) {
    const int n4 = N_NODES * (EMB_DIM / 4);
    int idx = blockIdx.x * blockDim.x + threadIdx.x;
    if (idx >= n4) return;
    float4 o = out[idx], a = h[idx];
    o.x = (o.x + a.x) * scale; o.y = (o.y + a.y) * scale;
    o.z = (o.z + a.z) * scale; o.w = (o.w + a.w) * scale;
    out[idx] = o;
}

extern "C" void kernel_launch(void* const* d_in, const int* in_sizes, int n_in,
                              void* d_out, int out_size, void* d_ws, size_t ws_size,
                              hipStream_t stream) {
    const float* user_emb = (const float*)d_in[0];
    const float* item_emb = (const float*)d_in[1];
    const int*   edge_row = (const int*)d_in[2];
    const int*   edge_col = (const int*)d_in[3];
    const float* edge_val = (const float*)d_in[4];
    float* out = (float*)d_out;

    const size_t H16_BYTES = (size_t)N_NODES * EMB_DIM * sizeof(__half);  // 38.4 MB

    char* ws = (char*)d_ws;
    __half* hA     = (__half*)ws;                      ws += H16_BYTES;
    __half* hB     = (__half*)ws;                      ws += H16_BYTES;
    unsigned long long* csr = (unsigned long long*)ws; ws += (size_t)NNZ * 8;
    int*   row_ptr = (int*)ws;                         ws += (size_t)(N_NODES + 4) * 4;
    int*   counts  = (int*)ws;                         ws += (size_t)N_NODES * 4;
    int*   partials= (int*)ws;                         ws += 4096;
    const size_t REQUIRED = (size_t)(ws - (char*)d_ws);

    const int blk     = 256;
    const int n4      = N_NODES * (EMB_DIM / 4);
    const int grid_n4 = (n4 + blk - 1) / blk;
    const float scales[3] = {1.0f, 1.0f, 0.25f};

    if (ws_size >= REQUIRED) {
        // ---- build packed, row-sorted CSR (coarse partition + fine scatter) ----
        // partials: coarse counts -> cbase[0..NCOARSE]; counts[0..NCOARSE): ccur
        zero_int_kernel<<<1, 512, 0, stream>>>(partials, NCOARSE + 1);
        zero_int_kernel<<<1, 512, 0, stream>>>(counts, NCOARSE);
        coarse_hist<<<P1_BLOCKS, 256, 0, stream>>>(edge_row, partials);
        coarse_scan<<<1, 512, 0, stream>>>(partials);
        // csr_tmp reuses hA/hB region (76.8 MB >= 40 MB), dead before init.
        unsigned long long* csr_tmp = (unsigned long long*)hA;
        partition_coarse<<<P1_BLOCKS, 256, 0, stream>>>(
            edge_row, edge_col, edge_val, partials, counts, csr_tmp);
        fine_scatter<<<NCOARSE, 1024, 0, stream>>>(partials, csr_tmp, csr, row_ptr);
        // ---- propagate (fp16 h, fp32 out accumulation) ----
        init_kernel<<<grid_n4, blk, 0, stream>>>(
            (const float4*)user_emb, (const float4*)item_emb, (uint2*)hA, (float4*)out);
        __half* h = hA; __half* hn = hB;
        const int grid_sp = (int)(((long long)N_NODES * 64) / blk);  // 75,000
        for (int layer = 0; layer < 3; ++layer) {
            spmm_pull_kernel<<<grid_sp, blk, 0, stream>>>(
                row_ptr, csr, h, hn, out, scales[layer]);
            __half* t = h; h = hn; hn = t;
        }
    } else {
        // fallback: fp32 push path (needs only 2 * 76.8 MB)
        float* hA32 = (float*)d_ws;
        float* hB32 = hA32 + (size_t)N_NODES * EMB_DIM;
        init32_kernel<<<grid_n4, blk, 0, stream>>>(
            (const float4*)user_emb, (const float4*)item_emb, (float4*)hA32, (float4*)out);
        float* h = hA32; float* hn = hB32;
        const int grid_sp = (int)(((long long)NNZ * 64) / blk);
        for (int layer = 0; layer < 3; ++layer) {
            zero4_kernel<<<grid_n4, blk, 0, stream>>>((float4*)hn);
            spmm_push_kernel<<<grid_sp, blk, 0, stream>>>(edge_row, edge_col, edge_val, h, hn);
            acc_kernel<<<grid_n4, blk, 0, stream>>>((float4*)out, (const float4*)hn, scales[layer]);
            float* t = h; h = hn; hn = t;
        }
    }
}

// Round 5
// 813.479 us; speedup vs baseline: 1.4305x; 1.0268x over previous
//
#include <hip/hip_runtime.h>
#include <hip/hip_fp16.h>
#include <hip/hip_bf16.h>

// LightGCN propagation on MI355X (gfx950).
// out = (h0 + A*h0 + A^2*h0 + A^3*h0)/4, A = COO(edge_row, edge_col, edge_val)
//
// Round 8: spmm was carrying a per-layer fp32 out RMW (76.8R + 76.8W each
// layer + 76.8W in init = 537 MB) for what is algebraically ONE final combine.
// Defer the accumulation:
//   init16: emb -> h0 fp16 only (no out write)
//   spmm_mid x2: y = fp16(A*x) only (no out access); layer 2 overwrites the
//     h0 buffer (h0 recomputed from fp32 inputs at the end) -> ws unchanged
//   spmm_last: acc = A*h2; out = (emb + h1 + h2 + acc) * 0.25, single NT write
// Build pipeline (round 6/7, verified): coarse_hist -> coarse_scan ->
// partition_coarse (per-(block,bin) run reservation; one XCD owns each run) ->
// fine_scatter (per-bin LDS hist + scan -> row_ptr + row-sorted CSR).
// word = val<<32 | col<<10 | row_local10; spmm unpacks col = lo >> 10.

#define NUM_USERS 200000
#define NUM_ITEMS 100000
#define N_NODES   300000
#define EMB_DIM   64
#define NNZ       5000000

#define COARSE_SHIFT 10
#define COARSE_ROWS  1024
#define NCOARSE      ((N_NODES + COARSE_ROWS - 1) / COARSE_ROWS)  // 293

#define P1_CHUNK  16384
#define P1_BLOCKS ((NNZ + P1_CHUNK - 1) / P1_CHUNK)               // 306

// ---------------------------------------------------------------------------
// init: h0 = ego (fp16, 4 dims packed per uint2). No out write.
// ---------------------------------------------------------------------------
__global__ void init16_kernel(const float4* __restrict__ user_emb,
                              const float4* __restrict__ item_emb,
                              uint2* __restrict__ h16) {
    const int n4 = N_NODES * (EMB_DIM / 4);
    int idx = blockIdx.x * blockDim.x + threadIdx.x;
    if (idx >= n4) return;
    const int user4 = NUM_USERS * (EMB_DIM / 4);
    float4 v = (idx < user4) ? user_emb[idx] : item_emb[idx - user4];
    __half2 p0 = __floats2half2_rn(v.x, v.y);
    __half2 p1 = __floats2half2_rn(v.z, v.w);
    uint2 u;
    u.x = *(unsigned int*)&p0;
    u.y = *(unsigned int*)&p1;
    h16[idx] = u;
}

// ---------------------------------------------------------------------------
// zero ints (counts / cursors)
// ---------------------------------------------------------------------------
__global__ void zero_int_kernel(int* __restrict__ p, int n) {
    int idx = blockIdx.x * blockDim.x + threadIdx.x;
    if (idx < n) p[idx] = 0;
}

// ---------------------------------------------------------------------------
// coarse histogram: LDS-privatized 293 bins, one global atomic per (block,bin)
// ---------------------------------------------------------------------------
__global__ void coarse_hist(const int* __restrict__ row, int* __restrict__ ccnt) {
    __shared__ int h[NCOARSE];
    int t = threadIdx.x;
    for (int j = t; j < NCOARSE; j += 256) h[j] = 0;
    __syncthreads();
    int start = blockIdx.x * P1_CHUNK;
    int end = min(start + P1_CHUNK, NNZ);
    for (int i = start + t; i < end; i += 256)
        atomicAdd(&h[(unsigned int)row[i] >> COARSE_SHIFT], 1);
    __syncthreads();
    for (int j = t; j < NCOARSE; j += 256)
        if (h[j] > 0) atomicAdd(&ccnt[j], h[j]);
}

// ---------------------------------------------------------------------------
// exclusive scan of 293 coarse counts -> cbase[0..293] (cbase[293] = NNZ)
// ---------------------------------------------------------------------------
__global__ void coarse_scan(int* __restrict__ p) {
    __shared__ int lds[512];
    int t = threadIdx.x;
    lds[t] = (t < NCOARSE) ? p[t] : 0;
    __syncthreads();
    for (int off = 1; off < 512; off <<= 1) {
        int v = (t >= off) ? lds[t - off] : 0;
        __syncthreads();
        lds[t] += v;
        __syncthreads();
    }
    if (t < NCOARSE) p[t] = (t > 0) ? lds[t - 1] : 0;
    if (t == 0) p[NCOARSE] = lds[NCOARSE - 1];
}

// ---------------------------------------------------------------------------
// pass 1: partition edges into 293 coarse bins (1024 rows each).
// Per (block, bin): one global atomicAdd reserves a contiguous run; all stores
// of a run come from this block -> full-line writebacks from one XCD's L2.
// word = val<<32 | col<<10 | row_local10
// ---------------------------------------------------------------------------
__global__ void partition_coarse(const int* __restrict__ row,
                                 const int* __restrict__ col,
                                 const float* __restrict__ val,
                                 const int* __restrict__ cbase,
                                 int* __restrict__ ccur,
                                 unsigned long long* __restrict__ tmp) {
    __shared__ int hist[NCOARSE];
    __shared__ int lbase[NCOARSE];
    __shared__ int lcur[NCOARSE];
    int t = threadIdx.x;
    int start = blockIdx.x * P1_CHUNK;
    int end = min(start + P1_CHUNK, NNZ);
    for (int j = t; j < NCOARSE; j += 256) { hist[j] = 0; lcur[j] = 0; }
    __syncthreads();
    for (int i = start + t; i < end; i += 256)
        atomicAdd(&hist[(unsigned int)row[i] >> COARSE_SHIFT], 1);
    __syncthreads();
    for (int j = t; j < NCOARSE; j += 256) {
        int c = hist[j];
        if (c > 0)
            lbase[j] = cbase[j] + atomicAdd(&ccur[j], c);
    }
    __syncthreads();
    for (int i = start + t; i < end; i += 256) {
        int r = row[i];
        int b = (int)((unsigned int)r >> COARSE_SHIFT);
        unsigned int lo = ((unsigned int)col[i] << 10) | ((unsigned int)r & 1023u);
        unsigned long long p = ((unsigned long long)__float_as_uint(val[i]) << 32)
                             | (unsigned long long)lo;
        int pos = lbase[b] + atomicAdd(&lcur[b], 1);
        tmp[pos] = p;
    }
}

// ---------------------------------------------------------------------------
// pass 2: one block per coarse bin. LDS histogram of the bin's region by
// row_local (no global atomics), block scan -> row_ptr for its 1024 rows,
// then scatter the region into final row-sorted CSR positions via LDS
// cursors. All traffic inside a ~137 KB L2-resident window, block-private.
// ---------------------------------------------------------------------------
__global__ void __launch_bounds__(1024)
fine_scatter(const int* __restrict__ cbase,
             const unsigned long long* __restrict__ tmp,
             unsigned long long* __restrict__ csr,
             int* __restrict__ row_ptr) {
    __shared__ int offs[COARSE_ROWS];
    __shared__ int cur[COARSE_ROWS];
    int t = threadIdx.x;
    int bin = blockIdx.x;
    int cstart = cbase[bin];
    int cend   = cbase[bin + 1];
    offs[t] = 0;
    cur[t] = 0;
    __syncthreads();
    for (int i = cstart + t; i < cend; i += 1024)
        atomicAdd(&offs[(unsigned int)tmp[i] & 1023u], 1);
    __syncthreads();
    int c = offs[t];
    // inclusive scan in place (Hillis-Steele)
    for (int off = 1; off < 1024; off <<= 1) {
        int v = (t >= off) ? offs[t - off] : 0;
        __syncthreads();
        offs[t] += v;
        __syncthreads();
    }
    int excl = offs[t] - c;
    __syncthreads();
    offs[t] = excl;      // offs[] now holds exclusive per-row offsets
    __syncthreads();
    int r = (bin << COARSE_SHIFT) + t;
    if (r < N_NODES) row_ptr[r] = cstart + excl;
    if (bin == NCOARSE - 1 && t == 0) row_ptr[N_NODES] = cend;
    for (int i = cstart + t; i < cend; i += 1024) {
        unsigned long long p = tmp[i];
        int rl = (int)((unsigned int)p & 1023u);
        int pos = cstart + offs[rl] + atomicAdd(&cur[rl], 1);
        csr[pos] = p;    // scattered within ~137 KB window (L2-resident)
    }
}

// ---------------------------------------------------------------------------
// pull SpMM mid-layer: one wave per row, lane = dim. fp16 gathers, fp32 acc.
// Writes y only (no out traffic).
// ---------------------------------------------------------------------------
__global__ void spmm_mid_kernel(const int* __restrict__ row_ptr,
                                const unsigned long long* __restrict__ csr,
                                const __half* __restrict__ x,
                                __half* __restrict__ y) {
    int gid  = blockIdx.x * blockDim.x + threadIdx.x;
    int wid  = gid >> 6;
    int lane = threadIdx.x & 63;
    if (wid >= N_NODES) return;
    wid = __builtin_amdgcn_readfirstlane(wid);  // force SGPR: scalar edge loads
    int s = row_ptr[wid];
    int e = row_ptr[wid + 1];
    float acc = 0.f;
    int k = s;
    for (; k + 4 <= e; k += 4) {
        unsigned long long p0 = csr[k];
        unsigned long long p1 = csr[k + 1];
        unsigned long long p2 = csr[k + 2];
        unsigned long long p3 = csr[k + 3];
        unsigned int c0 = (unsigned int)p0 >> 10, c1 = (unsigned int)p1 >> 10;
        unsigned int c2 = (unsigned int)p2 >> 10, c3 = (unsigned int)p3 >> 10;
        float v0 = __uint_as_float((unsigned int)(p0 >> 32));
        float v1 = __uint_as_float((unsigned int)(p1 >> 32));
        float v2 = __uint_as_float((unsigned int)(p2 >> 32));
        float v3 = __uint_as_float((unsigned int)(p3 >> 32));
        float x0 = __half2float(x[(c0 << 6) + lane]);
        float x1 = __half2float(x[(c1 << 6) + lane]);
        float x2 = __half2float(x[(c2 << 6) + lane]);
        float x3 = __half2float(x[(c3 << 6) + lane]);
        acc += v0 * x0;
        acc += v1 * x1;
        acc += v2 * x2;
        acc += v3 * x3;
    }
    for (; k < e; ++k) {
        unsigned long long p = csr[k];
        unsigned int c = (unsigned int)p >> 10;
        float v = __uint_as_float((unsigned int)(p >> 32));
        acc += v * __half2float(x[(c << 6) + lane]);
    }
    y[(wid << 6) + lane] = __float2half(acc);
}

// ---------------------------------------------------------------------------
// pull SpMM last layer, fused combine:
// out = (h0(emb fp32) + h1 + h2 + A*h2) * 0.25, single NT write, no y.
// ---------------------------------------------------------------------------
__global__ void spmm_last_kernel(const int* __restrict__ row_ptr,
                                 const unsigned long long* __restrict__ csr,
                                 const __half* __restrict__ x,    // h2
                                 const __half* __restrict__ h1,
                                 const float* __restrict__ user_emb,
                                 const float* __restrict__ item_emb,
                                 float* __restrict__ out) {
    int gid  = blockIdx.x * blockDim.x + threadIdx.x;
    int wid  = gid >> 6;
    int lane = threadIdx.x & 63;
    if (wid >= N_NODES) return;
    wid = __builtin_amdgcn_readfirstlane(wid);  // force SGPR: scalar edge loads
    int s = row_ptr[wid];
    int e = row_ptr[wid + 1];
    float acc = 0.f;
    int k = s;
    for (; k + 4 <= e; k += 4) {
        unsigned long long p0 = csr[k];
        unsigned long long p1 = csr[k + 1];
        unsigned long long p2 = csr[k + 2];
        unsigned long long p3 = csr[k + 3];
        unsigned int c0 = (unsigned int)p0 >> 10, c1 = (unsigned int)p1 >> 10;
        unsigned int c2 = (unsigned int)p2 >> 10, c3 = (unsigned int)p3 >> 10;
        float v0 = __uint_as_float((unsigned int)(p0 >> 32));
        float v1 = __uint_as_float((unsigned int)(p1 >> 32));
        float v2 = __uint_as_float((unsigned int)(p2 >> 32));
        float v3 = __uint_as_float((unsigned int)(p3 >> 32));
        float x0 = __half2float(x[(c0 << 6) + lane]);
        float x1 = __half2float(x[(c1 << 6) + lane]);
        float x2 = __half2float(x[(c2 << 6) + lane]);
        float x3 = __half2float(x[(c3 << 6) + lane]);
        acc += v0 * x0;
        acc += v1 * x1;
        acc += v2 * x2;
        acc += v3 * x3;
    }
    for (; k < e; ++k) {
        unsigned long long p = csr[k];
        unsigned int c = (unsigned int)p >> 10;
        float v = __uint_as_float((unsigned int)(p >> 32));
        acc += v * __half2float(x[(c << 6) + lane]);
    }
    int o = (wid << 6) + lane;
    float h0v = (o < NUM_USERS * EMB_DIM) ? user_emb[o]
                                          : item_emb[o - NUM_USERS * EMB_DIM];
    float h1v = __half2float(h1[o]);
    float h2v = __half2float(x[o]);
    __builtin_nontemporal_store((h0v + h1v + h2v + acc) * 0.25f, &out[o]);
}

// ---------------------------------------------------------------------------
// fallback (round-1 push path) if ws too small
// ---------------------------------------------------------------------------
__global__ void init32_kernel(const float4* __restrict__ user_emb,
                              const float4* __restrict__ item_emb,
                              float4* __restrict__ h,
                              float4* __restrict__ out) {
    const int n4 = N_NODES * (EMB_DIM / 4);
    int idx = blockIdx.x * blockDim.x + threadIdx.x;
    if (idx >= n4) return;
    const int user4 = NUM_USERS * (EMB_DIM / 4);
    float4 v = (idx < user4) ? user_emb[idx] : item_emb[idx - user4];
    h[idx] = v;
    out[idx] = v;
}
__global__ void zero4_kernel(float4* __restrict__ p) {
    const int n4 = N_NODES * (EMB_DIM / 4);
    int idx = blockIdx.x * blockDim.x + threadIdx.x;
    if (idx < n4) p[idx] = make_float4(0.f, 0.f, 0.f, 0.f);
}
__global__ void spmm_push_kernel(const int* __restrict__ row, const int* __restrict__ col,
                                 const float* __restrict__ val, const float* __restrict__ x,
                                 float* __restrict__ y) {
    unsigned int gid = blockIdx.x * blockDim.x + threadIdx.x;
    unsigned int e = gid >> 6, lane = gid & 63u;
    if (e >= NNZ) return;
    atomicAdd(&y[(unsigned int)row[e] * EMB_DIM + lane],
              val[e] * x[(unsigned int)col[e] * EMB_DIM + lane]);
}
__global__ void acc_kernel(float4* __restrict__ out, const float4* __restrict__ h, float scale) {
    const int n4 = N_NODES * (EMB_DIM / 4);
    int idx = blockIdx.x * blockDim.x + threadIdx.x;
    if (idx >= n4) return;
    float4 o = out[idx], a = h[idx];
    o.x = (o.x + a.x) * scale; o.y = (o.y + a.y) * scale;
    o.z = (o.z + a.z) * scale; o.w = (o.w + a.w) * scale;
    out[idx] = o;
}

extern "C" void kernel_launch(void* const* d_in, const int* in_sizes, int n_in,
                              void* d_out, int out_size, void* d_ws, size_t ws_size,
                              hipStream_t stream) {
    const float* user_emb = (const float*)d_in[0];
    const float* item_emb = (const float*)d_in[1];
    const int*   edge_row = (const int*)d_in[2];
    const int*   edge_col = (const int*)d_in[3];
    const float* edge_val = (const float*)d_in[4];
    float* out = (float*)d_out;

    const size_t H16_BYTES = (size_t)N_NODES * EMB_DIM * sizeof(__half);  // 38.4 MB

    char* ws = (char*)d_ws;
    __half* hA     = (__half*)ws;                      ws += H16_BYTES;
    __half* hB     = (__half*)ws;                      ws += H16_BYTES;
    unsigned long long* csr = (unsigned long long*)ws; ws += (size_t)NNZ * 8;
    int*   row_ptr = (int*)ws;                         ws += (size_t)(N_NODES + 4) * 4;
    int*   counts  = (int*)ws;                         ws += (size_t)N_NODES * 4;
    int*   partials= (int*)ws;                         ws += 4096;
    const size_t REQUIRED = (size_t)(ws - (char*)d_ws);

    const int blk     = 256;
    const int n4      = N_NODES * (EMB_DIM / 4);
    const int grid_n4 = (n4 + blk - 1) / blk;

    if (ws_size >= REQUIRED) {
        // ---- build packed, row-sorted CSR (coarse partition + fine scatter) ----
        // partials: coarse counts -> cbase[0..NCOARSE]; counts[0..NCOARSE): ccur
        zero_int_kernel<<<1, 512, 0, stream>>>(partials, NCOARSE + 1);
        zero_int_kernel<<<1, 512, 0, stream>>>(counts, NCOARSE);
        coarse_hist<<<P1_BLOCKS, 256, 0, stream>>>(edge_row, partials);
        coarse_scan<<<1, 512, 0, stream>>>(partials);
        // csr_tmp reuses hA/hB region (76.8 MB >= 40 MB), dead before init.
        unsigned long long* csr_tmp = (unsigned long long*)hA;
        partition_coarse<<<P1_BLOCKS, 256, 0, stream>>>(
            edge_row, edge_col, edge_val, partials, counts, csr_tmp);
        fine_scatter<<<NCOARSE, 1024, 0, stream>>>(partials, csr_tmp, csr, row_ptr);
        // ---- propagate: h0 -> h1 -> h2 -> fused final combine ----
        init16_kernel<<<grid_n4, blk, 0, stream>>>(
            (const float4*)user_emb, (const float4*)item_emb, (uint2*)hA);
        const int grid_sp = (int)(((long long)N_NODES * 64) / blk);  // 75,000
        spmm_mid_kernel<<<grid_sp, blk, 0, stream>>>(row_ptr, csr, hA, hB); // h1
        spmm_mid_kernel<<<grid_sp, blk, 0, stream>>>(row_ptr, csr, hB, hA); // h2 (over h0)
        spmm_last_kernel<<<grid_sp, blk, 0, stream>>>(
            row_ptr, csr, hA /*h2*/, hB /*h1*/, user_emb, item_emb, out);
    } else {
        // fallback: fp32 push path (needs only 2 * 76.8 MB)
        const float scales[3] = {1.0f, 1.0f, 0.25f};
        float* hA32 = (float*)d_ws;
        float* hB32 = hA32 + (size_t)N_NODES * EMB_DIM;
        init32_kernel<<<grid_n4, blk, 0, stream>>>(
            (const float4*)user_emb, (const float4*)item_emb, (float4*)hA32, (float4*)out);
        float* h = hA32; float* hn = hB32;
        const int grid_sp = (int)(((long long)NNZ * 64) / blk);
        for (int layer = 0; layer < 3; ++layer) {
            zero4_kernel<<<grid_n4, blk, 0, stream>>>((float4*)hn);
            spmm_push_kernel<<<grid_sp, blk, 0, stream>>>(edge_row, edge_col, edge_val, h, hn);
            acc_kernel<<<grid_n4, blk, 0, stream>>>((float4*)out, (const float4*)hn, scales[layer]);
            float* t = h; h = hn; hn = t;
        }
    }
}

// Round 7
// 721.190 us; speedup vs baseline: 1.6135x; 1.1280x over previous
//
#include <hip/hip_runtime.h>
#include <hip/hip_fp16.h>
#include <hip/hip_bf16.h>

// LightGCN propagation on MI355X (gfx950).
// out = (h0 + A*h0 + A^2*h0 + A^3*h0)/4, A = COO(edge_row, edge_col, edge_val)
//
// Round 10 = round 9 resubmit (container infra failure, no kernel verdict;
// same signature as round 3, which passed on identical resubmit in round 4).
// Round 9 design: spmm counters (3.0 TB/s, VALU 23%, occ 79%) say
// latency/MLP-bound, not BW-bound: gather traffic (373-409 MB/layer) is
// within 20% of the 8-XCD architectural floor (8 x 38.4 MB table), but only
// 4 gathers/wave were in flight -> unroll 8 (double MLP). Build phase: drop
// coarse_hist + a zero pass by appending into fixed-stride per-bin arenas
// (CAP = mean+57sigma); 1-block scan of final counts gives cbase;
// fine_scatter compacts arena -> csr (per-bin LDS hist+scan+scatter,
// contiguous both sides, block-owned runs -> full-line writebacks).
// Deferred-accumulation layering (round 8, verified):
//   init16: emb -> h0 fp16; spmm_mid x2 (y only); spmm_last fuses
//   out = (emb + h1 + h2 + A*h2) * 0.25, single NT write.
// word = val<<32 | col<<10 | row_local10; spmm unpacks col = lo >> 10.

#define NUM_USERS 200000
#define NUM_ITEMS 100000
#define N_NODES   300000
#define EMB_DIM   64
#define NNZ       5000000

#define COARSE_SHIFT 10
#define COARSE_ROWS  1024
#define NCOARSE      ((N_NODES + COARSE_ROWS - 1) / COARSE_ROWS)  // 293

#define ARENA_CAP 24576   // per-bin arena slots; mean 17067, sigma ~130 -> +57s

#define P1_CHUNK  16384
#define P1_BLOCKS ((NNZ + P1_CHUNK - 1) / P1_CHUNK)               // 306

// ---------------------------------------------------------------------------
// init: h0 = ego (fp16, 4 dims packed per uint2). No out write.
// ---------------------------------------------------------------------------
__global__ void init16_kernel(const float4* __restrict__ user_emb,
                              const float4* __restrict__ item_emb,
                              uint2* __restrict__ h16) {
    const int n4 = N_NODES * (EMB_DIM / 4);
    int idx = blockIdx.x * blockDim.x + threadIdx.x;
    if (idx >= n4) return;
    const int user4 = NUM_USERS * (EMB_DIM / 4);
    float4 v = (idx < user4) ? user_emb[idx] : item_emb[idx - user4];
    __half2 p0 = __floats2half2_rn(v.x, v.y);
    __half2 p1 = __floats2half2_rn(v.z, v.w);
    uint2 u;
    u.x = *(unsigned int*)&p0;
    u.y = *(unsigned int*)&p1;
    h16[idx] = u;
}

// ---------------------------------------------------------------------------
// zero ints (counts / cursors)
// ---------------------------------------------------------------------------
__global__ void zero_int_kernel(int* __restrict__ p, int n) {
    int idx = blockIdx.x * blockDim.x + threadIdx.x;
    if (idx < n) p[idx] = 0;
}

// ---------------------------------------------------------------------------
// pass 1: partition edges into 293 fixed-stride bin arenas (1024 rows/bin).
// Per (block, bin): LDS hist -> one global atomicAdd reserves a contiguous
// run in arena[bin*CAP ...]; all stores of a run come from this block -> one
// XCD owns each run -> full-line writebacks.
// word = val<<32 | col<<10 | row_local10
// ---------------------------------------------------------------------------
__global__ void partition_arena(const int* __restrict__ row,
                                const int* __restrict__ col,
                                const float* __restrict__ val,
                                int* __restrict__ ccur,
                                unsigned long long* __restrict__ arena) {
    __shared__ int hist[NCOARSE];
    __shared__ int lbase[NCOARSE];
    __shared__ int lcur[NCOARSE];
    int t = threadIdx.x;
    int start = blockIdx.x * P1_CHUNK;
    int end = min(start + P1_CHUNK, NNZ);
    for (int j = t; j < NCOARSE; j += 256) { hist[j] = 0; lcur[j] = 0; }
    __syncthreads();
    for (int i = start + t; i < end; i += 256)
        atomicAdd(&hist[(unsigned int)row[i] >> COARSE_SHIFT], 1);
    __syncthreads();
    for (int j = t; j < NCOARSE; j += 256) {
        int c = hist[j];
        if (c > 0)
            lbase[j] = j * ARENA_CAP + atomicAdd(&ccur[j], c);
    }
    __syncthreads();
    for (int i = start + t; i < end; i += 256) {
        int r = row[i];
        int b = (int)((unsigned int)r >> COARSE_SHIFT);
        unsigned int lo = ((unsigned int)col[i] << 10) | ((unsigned int)r & 1023u);
        unsigned long long p = ((unsigned long long)__float_as_uint(val[i]) << 32)
                             | (unsigned long long)lo;
        int pos = lbase[b] + atomicAdd(&lcur[b], 1);
        arena[pos] = p;
    }
}

// ---------------------------------------------------------------------------
// exclusive scan of 293 final bin counts -> cbase[0..293] (cbase[293] = NNZ)
// ---------------------------------------------------------------------------
__global__ void arena_scan(const int* __restrict__ cnt, int* __restrict__ cbase) {
    __shared__ int lds[512];
    int t = threadIdx.x;
    lds[t] = (t < NCOARSE) ? cnt[t] : 0;
    __syncthreads();
    for (int off = 1; off < 512; off <<= 1) {
        int v = (t >= off) ? lds[t - off] : 0;
        __syncthreads();
        lds[t] += v;
        __syncthreads();
    }
    if (t < NCOARSE) cbase[t] = (t > 0) ? lds[t - 1] : 0;
    if (t == 0) cbase[NCOARSE] = lds[NCOARSE - 1];
}

// ---------------------------------------------------------------------------
// pass 2: one block per coarse bin. LDS histogram of the bin's arena by
// row_local (no global atomics), block scan -> row_ptr for its 1024 rows,
// then compact arena -> final row-sorted CSR via LDS cursors. All writes
// block-private, scattered only within a ~137 KB L2-resident window.
// ---------------------------------------------------------------------------
__global__ void __launch_bounds__(1024)
fine_scatter(const int* __restrict__ cbase,
             const int* __restrict__ cnt,
             const unsigned long long* __restrict__ arena,
             unsigned long long* __restrict__ csr,
             int* __restrict__ row_ptr) {
    __shared__ int offs[COARSE_ROWS];
    __shared__ int cur[COARSE_ROWS];
    int t = threadIdx.x;
    int bin = blockIdx.x;
    int n = cnt[bin];
    int cstart = cbase[bin];
    const unsigned long long* src = arena + (size_t)bin * ARENA_CAP;
    offs[t] = 0;
    cur[t] = 0;
    __syncthreads();
    for (int i = t; i < n; i += 1024)
        atomicAdd(&offs[(unsigned int)src[i] & 1023u], 1);
    __syncthreads();
    int c = offs[t];
    // inclusive scan in place (Hillis-Steele)
    for (int off = 1; off < 1024; off <<= 1) {
        int v = (t >= off) ? offs[t - off] : 0;
        __syncthreads();
        offs[t] += v;
        __syncthreads();
    }
    int excl = offs[t] - c;
    __syncthreads();
    offs[t] = excl;      // offs[] now holds exclusive per-row offsets
    __syncthreads();
    int r = (bin << COARSE_SHIFT) + t;
    if (r < N_NODES) row_ptr[r] = cstart + excl;
    if (bin == NCOARSE - 1 && t == 0) row_ptr[N_NODES] = cbase[NCOARSE];
    for (int i = t; i < n; i += 1024) {
        unsigned long long p = src[i];
        int rl = (int)((unsigned int)p & 1023u);
        int pos = cstart + offs[rl] + atomicAdd(&cur[rl], 1);
        csr[pos] = p;    // scattered within ~137 KB window (L2-resident)
    }
}

// ---------------------------------------------------------------------------
// pull SpMM mid-layer: one wave per row, lane = dim. fp16 gathers, fp32 acc.
// Unroll 8: 8 gathers in flight per wave (latency/MLP-bound per counters).
// Writes y only (no out traffic).
// ---------------------------------------------------------------------------
__global__ void spmm_mid_kernel(const int* __restrict__ row_ptr,
                                const unsigned long long* __restrict__ csr,
                                const __half* __restrict__ x,
                                __half* __restrict__ y) {
    int gid  = blockIdx.x * blockDim.x + threadIdx.x;
    int wid  = gid >> 6;
    int lane = threadIdx.x & 63;
    if (wid >= N_NODES) return;
    wid = __builtin_amdgcn_readfirstlane(wid);  // force SGPR: scalar edge loads
    int s = row_ptr[wid];
    int e = row_ptr[wid + 1];
    float acc = 0.f;
    int k = s;
    for (; k + 8 <= e; k += 8) {
        unsigned long long p0 = csr[k];
        unsigned long long p1 = csr[k + 1];
        unsigned long long p2 = csr[k + 2];
        unsigned long long p3 = csr[k + 3];
        unsigned long long p4 = csr[k + 4];
        unsigned long long p5 = csr[k + 5];
        unsigned long long p6 = csr[k + 6];
        unsigned long long p7 = csr[k + 7];
        float x0 = __half2float(x[(((unsigned int)p0 >> 10) << 6) + lane]);
        float x1 = __half2float(x[(((unsigned int)p1 >> 10) << 6) + lane]);
        float x2 = __half2float(x[(((unsigned int)p2 >> 10) << 6) + lane]);
        float x3 = __half2float(x[(((unsigned int)p3 >> 10) << 6) + lane]);
        float x4 = __half2float(x[(((unsigned int)p4 >> 10) << 6) + lane]);
        float x5 = __half2float(x[(((unsigned int)p5 >> 10) << 6) + lane]);
        float x6 = __half2float(x[(((unsigned int)p6 >> 10) << 6) + lane]);
        float x7 = __half2float(x[(((unsigned int)p7 >> 10) << 6) + lane]);
        acc += __uint_as_float((unsigned int)(p0 >> 32)) * x0;
        acc += __uint_as_float((unsigned int)(p1 >> 32)) * x1;
        acc += __uint_as_float((unsigned int)(p2 >> 32)) * x2;
        acc += __uint_as_float((unsigned int)(p3 >> 32)) * x3;
        acc += __uint_as_float((unsigned int)(p4 >> 32)) * x4;
        acc += __uint_as_float((unsigned int)(p5 >> 32)) * x5;
        acc += __uint_as_float((unsigned int)(p6 >> 32)) * x6;
        acc += __uint_as_float((unsigned int)(p7 >> 32)) * x7;
    }
    for (; k + 4 <= e; k += 4) {
        unsigned long long p0 = csr[k];
        unsigned long long p1 = csr[k + 1];
        unsigned long long p2 = csr[k + 2];
        unsigned long long p3 = csr[k + 3];
        float x0 = __half2float(x[(((unsigned int)p0 >> 10) << 6) + lane]);
        float x1 = __half2float(x[(((unsigned int)p1 >> 10) << 6) + lane]);
        float x2 = __half2float(x[(((unsigned int)p2 >> 10) << 6) + lane]);
        float x3 = __half2float(x[(((unsigned int)p3 >> 10) << 6) + lane]);
        acc += __uint_as_float((unsigned int)(p0 >> 32)) * x0;
        acc += __uint_as_float((unsigned int)(p1 >> 32)) * x1;
        acc += __uint_as_float((unsigned int)(p2 >> 32)) * x2;
        acc += __uint_as_float((unsigned int)(p3 >> 32)) * x3;
    }
    for (; k < e; ++k) {
        unsigned long long p = csr[k];
        acc += __uint_as_float((unsigned int)(p >> 32))
             * __half2float(x[(((unsigned int)p >> 10) << 6) + lane]);
    }
    y[(wid << 6) + lane] = __float2half(acc);
}

// ---------------------------------------------------------------------------
// pull SpMM last layer, fused combine (unroll 8):
// out = (h0(emb fp32) + h1 + h2 + A*h2) * 0.25, single NT write, no y.
// ---------------------------------------------------------------------------
__global__ void spmm_last_kernel(const int* __restrict__ row_ptr,
                                 const unsigned long long* __restrict__ csr,
                                 const __half* __restrict__ x,    // h2
                                 const __half* __restrict__ h1,
                                 const float* __restrict__ user_emb,
                                 const float* __restrict__ item_emb,
                                 float* __restrict__ out) {
    int gid  = blockIdx.x * blockDim.x + threadIdx.x;
    int wid  = gid >> 6;
    int lane = threadIdx.x & 63;
    if (wid >= N_NODES) return;
    wid = __builtin_amdgcn_readfirstlane(wid);  // force SGPR: scalar edge loads
    int s = row_ptr[wid];
    int e = row_ptr[wid + 1];
    float acc = 0.f;
    int k = s;
    for (; k + 8 <= e; k += 8) {
        unsigned long long p0 = csr[k];
        unsigned long long p1 = csr[k + 1];
        unsigned long long p2 = csr[k + 2];
        unsigned long long p3 = csr[k + 3];
        unsigned long long p4 = csr[k + 4];
        unsigned long long p5 = csr[k + 5];
        unsigned long long p6 = csr[k + 6];
        unsigned long long p7 = csr[k + 7];
        float x0 = __half2float(x[(((unsigned int)p0 >> 10) << 6) + lane]);
        float x1 = __half2float(x[(((unsigned int)p1 >> 10) << 6) + lane]);
        float x2 = __half2float(x[(((unsigned int)p2 >> 10) << 6) + lane]);
        float x3 = __half2float(x[(((unsigned int)p3 >> 10) << 6) + lane]);
        float x4 = __half2float(x[(((unsigned int)p4 >> 10) << 6) + lane]);
        float x5 = __half2float(x[(((unsigned int)p5 >> 10) << 6) + lane]);
        float x6 = __half2float(x[(((unsigned int)p6 >> 10) << 6) + lane]);
        float x7 = __half2float(x[(((unsigned int)p7 >> 10) << 6) + lane]);
        acc += __uint_as_float((unsigned int)(p0 >> 32)) * x0;
        acc += __uint_as_float((unsigned int)(p1 >> 32)) * x1;
        acc += __uint_as_float((unsigned int)(p2 >> 32)) * x2;
        acc += __uint_as_float((unsigned int)(p3 >> 32)) * x3;
        acc += __uint_as_float((unsigned int)(p4 >> 32)) * x4;
        acc += __uint_as_float((unsigned int)(p5 >> 32)) * x5;
        acc += __uint_as_float((unsigned int)(p6 >> 32)) * x6;
        acc += __uint_as_float((unsigned int)(p7 >> 32)) * x7;
    }
    for (; k + 4 <= e; k += 4) {
        unsigned long long p0 = csr[k];
        unsigned long long p1 = csr[k + 1];
        unsigned long long p2 = csr[k + 2];
        unsigned long long p3 = csr[k + 3];
        float x0 = __half2float(x[(((unsigned int)p0 >> 10) << 6) + lane]);
        float x1 = __half2float(x[(((unsigned int)p1 >> 10) << 6) + lane]);
        float x2 = __half2float(x[(((unsigned int)p2 >> 10) << 6) + lane]);
        float x3 = __half2float(x[(((unsigned int)p3 >> 10) << 6) + lane]);
        acc += __uint_as_float((unsigned int)(p0 >> 32)) * x0;
        acc += __uint_as_float((unsigned int)(p1 >> 32)) * x1;
        acc += __uint_as_float((unsigned int)(p2 >> 32)) * x2;
        acc += __uint_as_float((unsigned int)(p3 >> 32)) * x3;
    }
    for (; k < e; ++k) {
        unsigned long long p = csr[k];
        acc += __uint_as_float((unsigned int)(p >> 32))
             * __half2float(x[(((unsigned int)p >> 10) << 6) + lane]);
    }
    int o = (wid << 6) + lane;
    float h0v = (o < NUM_USERS * EMB_DIM) ? user_emb[o]
                                          : item_emb[o - NUM_USERS * EMB_DIM];
    float h1v = __half2float(h1[o]);
    float h2v = __half2float(x[o]);
    __builtin_nontemporal_store((h0v + h1v + h2v + acc) * 0.25f, &out[o]);
}

// ---------------------------------------------------------------------------
// fallback (round-1 push path) if ws too small
// ---------------------------------------------------------------------------
__global__ void init32_kernel(const float4* __restrict__ user_emb,
                              const float4* __restrict__ item_emb,
                              float4* __restrict__ h,
                              float4* __restrict__ out) {
    const int n4 = N_NODES * (EMB_DIM / 4);
    int idx = blockIdx.x * blockDim.x + threadIdx.x;
    if (idx >= n4) return;
    const int user4 = NUM_USERS * (EMB_DIM / 4);
    float4 v = (idx < user4) ? user_emb[idx] : item_emb[idx - user4];
    h[idx] = v;
    out[idx] = v;
}
__global__ void zero4_kernel(float4* __restrict__ p) {
    const int n4 = N_NODES * (EMB_DIM / 4);
    int idx = blockIdx.x * blockDim.x + threadIdx.x;
    if (idx < n4) p[idx] = make_float4(0.f, 0.f, 0.f, 0.f);
}
__global__ void spmm_push_kernel(const int* __restrict__ row, const int* __restrict__ col,
                                 const float* __restrict__ val, const float* __restrict__ x,
                                 float* __restrict__ y) {
    unsigned int gid = blockIdx.x * blockDim.x + threadIdx.x;
    unsigned int e = gid >> 6, lane = gid & 63u;
    if (e >= NNZ) return;
    atomicAdd(&y[(unsigned int)row[e] * EMB_DIM + lane],
              val[e] * x[(unsigned int)col[e] * EMB_DIM + lane]);
}
__global__ void acc_kernel(float4* __restrict__ out, const float4* __restrict__ h, float scale) {
    const int n4 = N_NODES * (EMB_DIM / 4);
    int idx = blockIdx.x * blockDim.x + threadIdx.x;
    if (idx >= n4) return;
    float4 o = out[idx], a = h[idx];
    o.x = (o.x + a.x) * scale; o.y = (o.y + a.y) * scale;
    o.z = (o.z + a.z) * scale; o.w = (o.w + a.w) * scale;
    out[idx] = o;
}

extern "C" void kernel_launch(void* const* d_in, const int* in_sizes, int n_in,
                              void* d_out, int out_size, void* d_ws, size_t ws_size,
                              hipStream_t stream) {
    const float* user_emb = (const float*)d_in[0];
    const float* item_emb = (const float*)d_in[1];
    const int*   edge_row = (const int*)d_in[2];
    const int*   edge_col = (const int*)d_in[3];
    const float* edge_val = (const float*)d_in[4];
    float* out = (float*)d_out;

    const size_t H16_BYTES = (size_t)N_NODES * EMB_DIM * sizeof(__half);  // 38.4 MB

    char* ws = (char*)d_ws;
    __half* hA     = (__half*)ws;                      ws += H16_BYTES;
    __half* hB     = (__half*)ws;                      ws += H16_BYTES;
    unsigned long long* csr = (unsigned long long*)ws; ws += (size_t)NNZ * 8;
    int*   row_ptr = (int*)ws;                         ws += (size_t)(N_NODES + 4) * 4;
    int*   counts  = (int*)ws;                         ws += (size_t)N_NODES * 4;
    int*   partials= (int*)ws;                         ws += 4096;
    const size_t REQUIRED = (size_t)(ws - (char*)d_ws);

    const int blk     = 256;
    const int n4      = N_NODES * (EMB_DIM / 4);
    const int grid_n4 = (n4 + blk - 1) / blk;

    if (ws_size >= REQUIRED) {
        // ---- build packed, row-sorted CSR (arena partition + fine scatter) ----
        // counts[0..NCOARSE): bin cursors/counts; partials: cbase[0..NCOARSE]
        // arena reuses hA/hB region (57.6 MB <= 76.8 MB), dead before init.
        unsigned long long* arena = (unsigned long long*)hA;
        zero_int_kernel<<<1, 512, 0, stream>>>(counts, NCOARSE);
        partition_arena<<<P1_BLOCKS, 256, 0, stream>>>(
            edge_row, edge_col, edge_val, counts, arena);
        arena_scan<<<1, 512, 0, stream>>>(counts, partials);
        fine_scatter<<<NCOARSE, 1024, 0, stream>>>(partials, counts, arena,
                                                   csr, row_ptr);
        // ---- propagate: h0 -> h1 -> h2 -> fused final combine ----
        init16_kernel<<<grid_n4, blk, 0, stream>>>(
            (const float4*)user_emb, (const float4*)item_emb, (uint2*)hA);
        const int grid_sp = (int)(((long long)N_NODES * 64) / blk);  // 75,000
        spmm_mid_kernel<<<grid_sp, blk, 0, stream>>>(row_ptr, csr, hA, hB); // h1
        spmm_mid_kernel<<<grid_sp, blk, 0, stream>>>(row_ptr, csr, hB, hA); // h2 (over h0)
        spmm_last_kernel<<<grid_sp, blk, 0, stream>>>(
            row_ptr, csr, hA /*h2*/, hB /*h1*/, user_emb, item_emb, out);
    } else {
        // fallback: fp32 push path (needs only 2 * 76.8 MB)
        const float scales[3] = {1.0f, 1.0f, 0.25f};
        float* hA32 = (float*)d_ws;
        float* hB32 = hA32 + (size_t)N_NODES * EMB_DIM;
        init32_kernel<<<grid_n4, blk, 0, stream>>>(
            (const float4*)user_emb, (const float4*)item_emb, (float4*)hA32, (float4*)out);
        float* h = hA32; float* hn = hB32;
        const int grid_sp = (int)(((long long)NNZ * 64) / blk);
        for (int layer = 0; layer < 3; ++layer) {
            zero4_kernel<<<grid_n4, blk, 0, stream>>>((float4*)hn);
            spmm_push_kernel<<<grid_sp, blk, 0, stream>>>(edge_row, edge_col, edge_val, h, hn);
            acc_kernel<<<grid_n4, blk, 0, stream>>>((float4*)out, (const float4*)hn, scales[layer]);
            float* t = h; h = hn; hn = t;
        }
    }
}

// Round 8
// 649.884 us; speedup vs baseline: 1.7906x; 1.1097x over previous
//
#include <hip/hip_runtime.h>
#include <hip/hip_fp16.h>
#include <hip/hip_bf16.h>

// LightGCN propagation on MI355X (gfx950).
// out = (h0 + A*h0 + A^2*h0 + A^3*h0)/4, A = COO(edge_row, edge_col, edge_val)
//
// Round 11: spmm confirmed latency/MLP-bound (unroll-8: 165->144 us, 3.45 TB/s,
// VALU 26%) -> process 2 adjacent rows per wave with a joint 8+8 loop: 16
// gathers in flight for the bulk, 8 on tails, independent of row length.
// fine_scatter read its bin region twice from global (evicted between passes:
// ~64 x 137KB concurrent regions per XCD > 4MB L2) -> 512-row bins staged
// ONCE in dynamic LDS (76KB, 2 blocks/CU), hist+scan+scatter from LDS;
// global two-pass fallback branch for impossible n>FS_CAP bins.
// Build (verified r6-r10): partition_arena (block-owned runs -> full-line
// writebacks) -> arena_scan -> fine_scatter -> row-sorted CSR + row_ptr.
// Deferred accumulation (r8): init16 -> spmm_mid x2 (y only) -> spmm_last
// fuses out = (emb + h1 + h2 + A*h2) * 0.25, single NT write.
// word = val<<32 | col<<9 | row_local9; spmm unpacks col = lo >> 9.

#define NUM_USERS 200000
#define NUM_ITEMS 100000
#define N_NODES   300000
#define EMB_DIM   64
#define NNZ       5000000

#define COARSE_SHIFT 9
#define COARSE_ROWS  512
#define NCOARSE      ((N_NODES + COARSE_ROWS - 1) / COARSE_ROWS)  // 586

#define ARENA_CAP 12288   // per-bin slots; mean 8532, sigma ~92 -> +40 sigma
#define FS_CAP    9216    // LDS-staged bin cap; mean+7.4 sigma, fallback below
#define FS_SHMEM  (FS_CAP * 8 + 2 * COARSE_ROWS * 4)              // 77824 B

#define P1_CHUNK  16384
#define P1_BLOCKS ((NNZ + P1_CHUNK - 1) / P1_CHUNK)               // 306

typedef unsigned long long u64;

// ---------------------------------------------------------------------------
// init: h0 = ego (fp16, 4 dims packed per uint2). No out write.
// ---------------------------------------------------------------------------
__global__ void init16_kernel(const float4* __restrict__ user_emb,
                              const float4* __restrict__ item_emb,
                              uint2* __restrict__ h16) {
    const int n4 = N_NODES * (EMB_DIM / 4);
    int idx = blockIdx.x * blockDim.x + threadIdx.x;
    if (idx >= n4) return;
    const int user4 = NUM_USERS * (EMB_DIM / 4);
    float4 v = (idx < user4) ? user_emb[idx] : item_emb[idx - user4];
    __half2 p0 = __floats2half2_rn(v.x, v.y);
    __half2 p1 = __floats2half2_rn(v.z, v.w);
    uint2 u;
    u.x = *(unsigned int*)&p0;
    u.y = *(unsigned int*)&p1;
    h16[idx] = u;
}

// ---------------------------------------------------------------------------
// zero ints (counts / cursors)
// ---------------------------------------------------------------------------
__global__ void zero_int_kernel(int* __restrict__ p, int n) {
    int idx = blockIdx.x * blockDim.x + threadIdx.x;
    if (idx < n) p[idx] = 0;
}

// ---------------------------------------------------------------------------
// pass 1: partition edges into 586 fixed-stride bin arenas (512 rows/bin).
// Per (block, bin): LDS hist -> one global atomicAdd reserves a contiguous
// run in arena[bin*CAP ...]; all stores of a run come from this block -> one
// XCD owns each run -> full-line writebacks.
// word = val<<32 | col<<9 | row_local9
// ---------------------------------------------------------------------------
__global__ void partition_arena(const int* __restrict__ row,
                                const int* __restrict__ col,
                                const float* __restrict__ val,
                                int* __restrict__ ccur,
                                u64* __restrict__ arena) {
    __shared__ int hist[NCOARSE];
    __shared__ int lbase[NCOARSE];
    __shared__ int lcur[NCOARSE];
    int t = threadIdx.x;
    int start = blockIdx.x * P1_CHUNK;
    int end = min(start + P1_CHUNK, NNZ);
    for (int j = t; j < NCOARSE; j += 256) { hist[j] = 0; lcur[j] = 0; }
    __syncthreads();
    for (int i = start + t; i < end; i += 256)
        atomicAdd(&hist[(unsigned int)row[i] >> COARSE_SHIFT], 1);
    __syncthreads();
    for (int j = t; j < NCOARSE; j += 256) {
        int c = hist[j];
        if (c > 0)
            lbase[j] = j * ARENA_CAP + atomicAdd(&ccur[j], c);
    }
    __syncthreads();
    for (int i = start + t; i < end; i += 256) {
        int r = row[i];
        int b = (int)((unsigned int)r >> COARSE_SHIFT);
        unsigned int lo = ((unsigned int)col[i] << 9) | ((unsigned int)r & 511u);
        u64 p = ((u64)__float_as_uint(val[i]) << 32) | (u64)lo;
        int pos = lbase[b] + atomicAdd(&lcur[b], 1);
        arena[pos] = p;
    }
}

// ---------------------------------------------------------------------------
// exclusive scan of 586 final bin counts -> cbase[0..586] (cbase[586] = NNZ)
// ---------------------------------------------------------------------------
__global__ void __launch_bounds__(1024)
arena_scan(const int* __restrict__ cnt, int* __restrict__ cbase) {
    __shared__ int lds[1024];
    int t = threadIdx.x;
    lds[t] = (t < NCOARSE) ? cnt[t] : 0;
    __syncthreads();
    for (int off = 1; off < 1024; off <<= 1) {
        int v = (t >= off) ? lds[t - off] : 0;
        __syncthreads();
        lds[t] += v;
        __syncthreads();
    }
    if (t < NCOARSE) cbase[t] = (t > 0) ? lds[t - 1] : 0;
    if (t == 0) cbase[NCOARSE] = lds[NCOARSE - 1];
}

// ---------------------------------------------------------------------------
// pass 2: one block per 512-row bin. Stage the bin's arena region ONCE in
// dynamic LDS, LDS hist by row_local -> block scan -> row_ptr, then scatter
// LDS -> final row-sorted CSR (block-private ~70KB window). Fallback branch:
// global two-pass for (statistically unreachable) n > FS_CAP.
// ---------------------------------------------------------------------------
__global__ void __launch_bounds__(1024)
fine_scatter(const int* __restrict__ cbase,
             const int* __restrict__ cnt,
             const u64* __restrict__ arena,
             u64* __restrict__ csr,
             int* __restrict__ row_ptr) {
    extern __shared__ u64 smem[];
    u64* buf  = smem;
    int* offs = (int*)&smem[FS_CAP];
    int* cur  = offs + COARSE_ROWS;
    int t = threadIdx.x;
    int bin = blockIdx.x;
    int n = cnt[bin];
    int cstart = cbase[bin];
    const u64* src = arena + (size_t)bin * ARENA_CAP;
    if (t < COARSE_ROWS) { offs[t] = 0; cur[t] = 0; }
    __syncthreads();
    if (n <= FS_CAP) {
        for (int i = t; i < n; i += 1024) {
            u64 p = src[i];
            buf[i] = p;
            atomicAdd(&offs[(unsigned int)p & 511u], 1);
        }
        __syncthreads();
        int c = (t < COARSE_ROWS) ? offs[t] : 0;
        for (int off = 1; off < COARSE_ROWS; off <<= 1) {
            int v = (t >= off && t < COARSE_ROWS) ? offs[t - off] : 0;
            __syncthreads();
            if (t < COARSE_ROWS) offs[t] += v;
            __syncthreads();
        }
        int excl = (t < COARSE_ROWS) ? offs[t] - c : 0;
        __syncthreads();
        if (t < COARSE_ROWS) offs[t] = excl;
        __syncthreads();
        int r = (bin << COARSE_SHIFT) + t;
        if (t < COARSE_ROWS && r < N_NODES) row_ptr[r] = cstart + excl;
        if (bin == NCOARSE - 1 && t == 0) row_ptr[N_NODES] = cbase[NCOARSE];
        for (int i = t; i < n; i += 1024) {
            u64 p = buf[i];
            int rl = (int)((unsigned int)p & 511u);
            int pos = cstart + offs[rl] + atomicAdd(&cur[rl], 1);
            csr[pos] = p;
        }
    } else {
        // fallback: global two-pass (same semantics, no LDS staging)
        for (int i = t; i < n; i += 1024)
            atomicAdd(&offs[(unsigned int)src[i] & 511u], 1);
        __syncthreads();
        int c = (t < COARSE_ROWS) ? offs[t] : 0;
        for (int off = 1; off < COARSE_ROWS; off <<= 1) {
            int v = (t >= off && t < COARSE_ROWS) ? offs[t - off] : 0;
            __syncthreads();
            if (t < COARSE_ROWS) offs[t] += v;
            __syncthreads();
        }
        int excl = (t < COARSE_ROWS) ? offs[t] - c : 0;
        __syncthreads();
        if (t < COARSE_ROWS) offs[t] = excl;
        __syncthreads();
        int r = (bin << COARSE_SHIFT) + t;
        if (t < COARSE_ROWS && r < N_NODES) row_ptr[r] = cstart + excl;
        if (bin == NCOARSE - 1 && t == 0) row_ptr[N_NODES] = cbase[NCOARSE];
        for (int i = t; i < n; i += 1024) {
            u64 p = src[i];
            int rl = (int)((unsigned int)p & 511u);
            int pos = cstart + offs[rl] + atomicAdd(&cur[rl], 1);
            csr[pos] = p;
        }
    }
}

// ---------------------------------------------------------------------------
// pair-row gather core: two adjacent rows per wave, joint 8+8 loop
// (16 gathers in flight), then per-row 8/4/1 tails.
// edge word: val<<32 | col<<9 | row_local9  ->  col = low32 >> 9
// ---------------------------------------------------------------------------
__device__ __forceinline__ void tail_accum(const u64* __restrict__ csr,
                                           const __half* __restrict__ x,
                                           int lane, int k, int e, float& acc) {
    for (; k + 8 <= e; k += 8) {
        u64 p0 = csr[k],     p1 = csr[k + 1], p2 = csr[k + 2], p3 = csr[k + 3];
        u64 p4 = csr[k + 4], p5 = csr[k + 5], p6 = csr[k + 6], p7 = csr[k + 7];
        float x0 = __half2float(x[(((unsigned int)p0 >> 9) << 6) + lane]);
        float x1 = __half2float(x[(((unsigned int)p1 >> 9) << 6) + lane]);
        float x2 = __half2float(x[(((unsigned int)p2 >> 9) << 6) + lane]);
        float x3 = __half2float(x[(((unsigned int)p3 >> 9) << 6) + lane]);
        float x4 = __half2float(x[(((unsigned int)p4 >> 9) << 6) + lane]);
        float x5 = __half2float(x[(((unsigned int)p5 >> 9) << 6) + lane]);
        float x6 = __half2float(x[(((unsigned int)p6 >> 9) << 6) + lane]);
        float x7 = __half2float(x[(((unsigned int)p7 >> 9) << 6) + lane]);
        acc += __uint_as_float((unsigned int)(p0 >> 32)) * x0;
        acc += __uint_as_float((unsigned int)(p1 >> 32)) * x1;
        acc += __uint_as_float((unsigned int)(p2 >> 32)) * x2;
        acc += __uint_as_float((unsigned int)(p3 >> 32)) * x3;
        acc += __uint_as_float((unsigned int)(p4 >> 32)) * x4;
        acc += __uint_as_float((unsigned int)(p5 >> 32)) * x5;
        acc += __uint_as_float((unsigned int)(p6 >> 32)) * x6;
        acc += __uint_as_float((unsigned int)(p7 >> 32)) * x7;
    }
    for (; k + 4 <= e; k += 4) {
        u64 p0 = csr[k], p1 = csr[k + 1], p2 = csr[k + 2], p3 = csr[k + 3];
        float x0 = __half2float(x[(((unsigned int)p0 >> 9) << 6) + lane]);
        float x1 = __half2float(x[(((unsigned int)p1 >> 9) << 6) + lane]);
        float x2 = __half2float(x[(((unsigned int)p2 >> 9) << 6) + lane]);
        float x3 = __half2float(x[(((unsigned int)p3 >> 9) << 6) + lane]);
        acc += __uint_as_float((unsigned int)(p0 >> 32)) * x0;
        acc += __uint_as_float((unsigned int)(p1 >> 32)) * x1;
        acc += __uint_as_float((unsigned int)(p2 >> 32)) * x2;
        acc += __uint_as_float((unsigned int)(p3 >> 32)) * x3;
    }
    for (; k < e; ++k) {
        u64 p = csr[k];
        acc += __uint_as_float((unsigned int)(p >> 32))
             * __half2float(x[(((unsigned int)p >> 9) << 6) + lane]);
    }
}

__device__ __forceinline__ void pair_accum(const int* __restrict__ row_ptr,
                                           const u64* __restrict__ csr,
                                           const __half* __restrict__ x,
                                           int lane, int r0,
                                           float& acc0, float& acc1) {
    int s0 = row_ptr[r0];
    int e0 = row_ptr[r0 + 1];
    int e1 = row_ptr[r0 + 2];
    int k0 = s0, k1 = e0;
    while (k0 + 8 <= e0 && k1 + 8 <= e1) {
        u64 p0 = csr[k0],     p1 = csr[k0 + 1], p2 = csr[k0 + 2], p3 = csr[k0 + 3];
        u64 p4 = csr[k0 + 4], p5 = csr[k0 + 5], p6 = csr[k0 + 6], p7 = csr[k0 + 7];
        u64 q0 = csr[k1],     q1 = csr[k1 + 1], q2 = csr[k1 + 2], q3 = csr[k1 + 3];
        u64 q4 = csr[k1 + 4], q5 = csr[k1 + 5], q6 = csr[k1 + 6], q7 = csr[k1 + 7];
        float a0 = __half2float(x[(((unsigned int)p0 >> 9) << 6) + lane]);
        float a1 = __half2float(x[(((unsigned int)p1 >> 9) << 6) + lane]);
        float a2 = __half2float(x[(((unsigned int)p2 >> 9) << 6) + lane]);
        float a3 = __half2float(x[(((unsigned int)p3 >> 9) << 6) + lane]);
        float a4 = __half2float(x[(((unsigned int)p4 >> 9) << 6) + lane]);
        float a5 = __half2float(x[(((unsigned int)p5 >> 9) << 6) + lane]);
        float a6 = __half2float(x[(((unsigned int)p6 >> 9) << 6) + lane]);
        float a7 = __half2float(x[(((unsigned int)p7 >> 9) << 6) + lane]);
        float b0 = __half2float(x[(((unsigned int)q0 >> 9) << 6) + lane]);
        float b1 = __half2float(x[(((unsigned int)q1 >> 9) << 6) + lane]);
        float b2 = __half2float(x[(((unsigned int)q2 >> 9) << 6) + lane]);
        float b3 = __half2float(x[(((unsigned int)q3 >> 9) << 6) + lane]);
        float b4 = __half2float(x[(((unsigned int)q4 >> 9) << 6) + lane]);
        float b5 = __half2float(x[(((unsigned int)q5 >> 9) << 6) + lane]);
        float b6 = __half2float(x[(((unsigned int)q6 >> 9) << 6) + lane]);
        float b7 = __half2float(x[(((unsigned int)q7 >> 9) << 6) + lane]);
        acc0 += __uint_as_float((unsigned int)(p0 >> 32)) * a0;
        acc0 += __uint_as_float((unsigned int)(p1 >> 32)) * a1;
        acc0 += __uint_as_float((unsigned int)(p2 >> 32)) * a2;
        acc0 += __uint_as_float((unsigned int)(p3 >> 32)) * a3;
        acc0 += __uint_as_float((unsigned int)(p4 >> 32)) * a4;
        acc0 += __uint_as_float((unsigned int)(p5 >> 32)) * a5;
        acc0 += __uint_as_float((unsigned int)(p6 >> 32)) * a6;
        acc0 += __uint_as_float((unsigned int)(p7 >> 32)) * a7;
        acc1 += __uint_as_float((unsigned int)(q0 >> 32)) * b0;
        acc1 += __uint_as_float((unsigned int)(q1 >> 32)) * b1;
        acc1 += __uint_as_float((unsigned int)(q2 >> 32)) * b2;
        acc1 += __uint_as_float((unsigned int)(q3 >> 32)) * b3;
        acc1 += __uint_as_float((unsigned int)(q4 >> 32)) * b4;
        acc1 += __uint_as_float((unsigned int)(q5 >> 32)) * b5;
        acc1 += __uint_as_float((unsigned int)(q6 >> 32)) * b6;
        acc1 += __uint_as_float((unsigned int)(q7 >> 32)) * b7;
        k0 += 8; k1 += 8;
    }
    tail_accum(csr, x, lane, k0, e0, acc0);
    tail_accum(csr, x, lane, k1, e1, acc1);
}

// ---------------------------------------------------------------------------
// pull SpMM mid-layer: two rows per wave, lane = dim. Writes y only.
// ---------------------------------------------------------------------------
__global__ void spmm_mid_kernel(const int* __restrict__ row_ptr,
                                const u64* __restrict__ csr,
                                const __half* __restrict__ x,
                                __half* __restrict__ y) {
    int gid  = blockIdx.x * blockDim.x + threadIdx.x;
    int r0   = (gid >> 6) * 2;
    int lane = threadIdx.x & 63;
    if (r0 >= N_NODES) return;
    r0 = __builtin_amdgcn_readfirstlane(r0);  // force SGPR: scalar edge loads
    float acc0 = 0.f, acc1 = 0.f;
    pair_accum(row_ptr, csr, x, lane, r0, acc0, acc1);
    int o = (r0 << 6) + lane;
    y[o]      = __float2half(acc0);
    y[o + 64] = __float2half(acc1);
}

// ---------------------------------------------------------------------------
// pull SpMM last layer, fused combine (two rows per wave):
// out = (h0(emb fp32) + h1 + h2 + A*h2) * 0.25, single NT write, no y.
// ---------------------------------------------------------------------------
__global__ void spmm_last_kernel(const int* __restrict__ row_ptr,
                                 const u64* __restrict__ csr,
                                 const __half* __restrict__ x,    // h2
                                 const __half* __restrict__ h1,
                                 const float* __restrict__ user_emb,
                                 const float* __restrict__ item_emb,
                                 float* __restrict__ out) {
    int gid  = blockIdx.x * blockDim.x + threadIdx.x;
    int r0   = (gid >> 6) * 2;
    int lane = threadIdx.x & 63;
    if (r0 >= N_NODES) return;
    r0 = __builtin_amdgcn_readfirstlane(r0);  // force SGPR: scalar edge loads
    float acc0 = 0.f, acc1 = 0.f;
    pair_accum(row_ptr, csr, x, lane, r0, acc0, acc1);
    int o0 = (r0 << 6) + lane;
    int o1 = o0 + 64;
    float h00 = (o0 < NUM_USERS * EMB_DIM) ? user_emb[o0]
                                           : item_emb[o0 - NUM_USERS * EMB_DIM];
    float h01 = (o1 < NUM_USERS * EMB_DIM) ? user_emb[o1]
                                           : item_emb[o1 - NUM_USERS * EMB_DIM];
    float r0v = (h00 + __half2float(h1[o0]) + __half2float(x[o0]) + acc0) * 0.25f;
    float r1v = (h01 + __half2float(h1[o1]) + __half2float(x[o1]) + acc1) * 0.25f;
    __builtin_nontemporal_store(r0v, &out[o0]);
    __builtin_nontemporal_store(r1v, &out[o1]);
}

// ---------------------------------------------------------------------------
// fallback (round-1 push path) if ws too small
// ---------------------------------------------------------------------------
__global__ void init32_kernel(const float4* __restrict__ user_emb,
                              const float4* __restrict__ item_emb,
                              float4* __restrict__ h,
                              float4* __restrict__ out) {
    const int n4 = N_NODES * (EMB_DIM / 4);
    int idx = blockIdx.x * blockDim.x + threadIdx.x;
    if (idx >= n4) return;
    const int user4 = NUM_USERS * (EMB_DIM / 4);
    float4 v = (idx < user4) ? user_emb[idx] : item_emb[idx - user4];
    h[idx] = v;
    out[idx] = v;
}
__global__ void zero4_kernel(float4* __restrict__ p) {
    const int n4 = N_NODES * (EMB_DIM / 4);
    int idx = blockIdx.x * blockDim.x + threadIdx.x;
    if (idx < n4) p[idx] = make_float4(0.f, 0.f, 0.f, 0.f);
}
__global__ void spmm_push_kernel(const int* __restrict__ row, const int* __restrict__ col,
                                 const float* __restrict__ val, const float* __restrict__ x,
                                 float* __restrict__ y) {
    unsigned int gid = blockIdx.x * blockDim.x + threadIdx.x;
    unsigned int e = gid >> 6, lane = gid & 63u;
    if (e >= NNZ) return;
    atomicAdd(&y[(unsigned int)row[e] * EMB_DIM + lane],
              val[e] * x[(unsigned int)col[e] * EMB_DIM + lane]);
}
__global__ void acc_kernel(float4* __restrict__ out, const float4* __restrict__ h, float scale) {
    const int n4 = N_NODES * (EMB_DIM / 4);
    int idx = blockIdx.x * blockDim.x + threadIdx.x;
    if (idx >= n4) return;
    float4 o = out[idx], a = h[idx];
    o.x = (o.x + a.x) * scale; o.y = (o.y + a.y) * scale;
    o.z = (o.z + a.z) * scale; o.w = (o.w + a.w) * scale;
    out[idx] = o;
}

extern "C" void kernel_launch(void* const* d_in, const int* in_sizes, int n_in,
                              void* d_out, int out_size, void* d_ws, size_t ws_size,
                              hipStream_t stream) {
    const float* user_emb = (const float*)d_in[0];
    const float* item_emb = (const float*)d_in[1];
    const int*   edge_row = (const int*)d_in[2];
    const int*   edge_col = (const int*)d_in[3];
    const float* edge_val = (const float*)d_in[4];
    float* out = (float*)d_out;

    const size_t H16_BYTES = (size_t)N_NODES * EMB_DIM * sizeof(__half);  // 38.4 MB

    char* ws = (char*)d_ws;
    __half* hA     = (__half*)ws;                      ws += H16_BYTES;
    __half* hB     = (__half*)ws;                      ws += H16_BYTES;
    u64*    csr    = (u64*)ws;                         ws += (size_t)NNZ * 8;
    int*   row_ptr = (int*)ws;                         ws += (size_t)(N_NODES + 4) * 4;
    int*   counts  = (int*)ws;                         ws += (size_t)N_NODES * 4;
    int*   partials= (int*)ws;                         ws += 4096;
    const size_t REQUIRED = (size_t)(ws - (char*)d_ws);

    const int blk     = 256;
    const int n4      = N_NODES * (EMB_DIM / 4);
    const int grid_n4 = (n4 + blk - 1) / blk;

    if (ws_size >= REQUIRED) {
        // ---- build packed, row-sorted CSR (arena partition + fine scatter) ----
        // counts[0..NCOARSE): bin cursors/counts; partials: cbase[0..NCOARSE]
        // arena reuses hA/hB region (57.6 MB <= 76.8 MB), dead before init.
        u64* arena = (u64*)hA;
        zero_int_kernel<<<1, 1024, 0, stream>>>(counts, NCOARSE);
        partition_arena<<<P1_BLOCKS, 256, 0, stream>>>(
            edge_row, edge_col, edge_val, counts, arena);
        arena_scan<<<1, 1024, 0, stream>>>(counts, partials);
        fine_scatter<<<NCOARSE, 1024, FS_SHMEM, stream>>>(partials, counts, arena,
                                                          csr, row_ptr);
        // ---- propagate: h0 -> h1 -> h2 -> fused final combine ----
        init16_kernel<<<grid_n4, blk, 0, stream>>>(
            (const float4*)user_emb, (const float4*)item_emb, (uint2*)hA);
        const int grid_sp = (int)(((long long)(N_NODES / 2) * 64) / blk);  // 37,500
        spmm_mid_kernel<<<grid_sp, blk, 0, stream>>>(row_ptr, csr, hA, hB); // h1
        spmm_mid_kernel<<<grid_sp, blk, 0, stream>>>(row_ptr, csr, hB, hA); // h2 (over h0)
        spmm_last_kernel<<<grid_sp, blk, 0, stream>>>(
            row_ptr, csr, hA /*h2*/, hB /*h1*/, user_emb, item_emb, out);
    } else {
        // fallback: fp32 push path (needs only 2 * 76.8 MB)
        const float scales[3] = {1.0f, 1.0f, 0.25f};
        float* hA32 = (float*)d_ws;
        float* hB32 = hA32 + (size_t)N_NODES * EMB_DIM;
        init32_kernel<<<grid_n4, blk, 0, stream>>>(
            (const float4*)user_emb, (const float4*)item_emb, (float4*)hA32, (float4*)out);
        float* h = hA32; float* hn = hB32;
        const int grid_sp = (int)(((long long)NNZ * 64) / blk);
        for (int layer = 0; layer < 3; ++layer) {
            zero4_kernel<<<grid_n4, blk, 0, stream>>>((float4*)hn);
            spmm_push_kernel<<<grid_sp, blk, 0, stream>>>(edge_row, edge_col, edge_val, h, hn);
            acc_kernel<<<grid_n4, blk, 0, stream>>>((float4*)out, (const float4*)hn, scales[layer]);
            float* t = h; h = hn; hn = t;
        }
    }
}

// Round 9
// 631.922 us; speedup vs baseline: 1.8415x; 1.0284x over previous
//
#include <hip/hip_runtime.h>
#include <hip/hip_fp16.h>
#include <hip/hip_bf16.h>

// LightGCN propagation on MI355X (gfx950).
// out = (h0 + A*h0 + A^2*h0 + A^3*h0)/4, A = COO(edge_row, edge_col, edge_val)
//
// Round 12: partition_arena ran at 10.6% occupancy (306 blocks x 256 thr =
// 4.8 waves/CU) -- pure latency chain with no hiding; 142 us at 1.1 TB/s.
// Fix: 1024 threads/block (same grid, same LDS, same reservation scheme)
// -> ~19 waves/CU. Everything else identical to the round-11 passing kernel.
// Build (verified): partition_arena (block-owned runs) -> arena_scan ->
// fine_scatter (LDS-staged 512-row bins) -> row-sorted CSR + row_ptr.
// Propagation (verified): init16 -> spmm_mid x2 (pair-row, 16 gathers in
// flight) -> spmm_last fused out = (emb + h1 + h2 + A*h2) * 0.25.
// word = val<<32 | col<<9 | row_local9; spmm unpacks col = lo >> 9.

#define NUM_USERS 200000
#define NUM_ITEMS 100000
#define N_NODES   300000
#define EMB_DIM   64
#define NNZ       5000000

#define COARSE_SHIFT 9
#define COARSE_ROWS  512
#define NCOARSE      ((N_NODES + COARSE_ROWS - 1) / COARSE_ROWS)  // 586

#define ARENA_CAP 12288   // per-bin slots; mean 8532, sigma ~92 -> +40 sigma
#define FS_CAP    9216    // LDS-staged bin cap; mean+7.4 sigma, fallback below
#define FS_SHMEM  (FS_CAP * 8 + 2 * COARSE_ROWS * 4)              // 77824 B

#define P1_CHUNK  16384
#define P1_BLOCKS ((NNZ + P1_CHUNK - 1) / P1_CHUNK)               // 306
#define P1_THREADS 1024

typedef unsigned long long u64;

// ---------------------------------------------------------------------------
// init: h0 = ego (fp16, 4 dims packed per uint2). No out write.
// ---------------------------------------------------------------------------
__global__ void init16_kernel(const float4* __restrict__ user_emb,
                              const float4* __restrict__ item_emb,
                              uint2* __restrict__ h16) {
    const int n4 = N_NODES * (EMB_DIM / 4);
    int idx = blockIdx.x * blockDim.x + threadIdx.x;
    if (idx >= n4) return;
    const int user4 = NUM_USERS * (EMB_DIM / 4);
    float4 v = (idx < user4) ? user_emb[idx] : item_emb[idx - user4];
    __half2 p0 = __floats2half2_rn(v.x, v.y);
    __half2 p1 = __floats2half2_rn(v.z, v.w);
    uint2 u;
    u.x = *(unsigned int*)&p0;
    u.y = *(unsigned int*)&p1;
    h16[idx] = u;
}

// ---------------------------------------------------------------------------
// zero ints (counts / cursors)
// ---------------------------------------------------------------------------
__global__ void zero_int_kernel(int* __restrict__ p, int n) {
    int idx = blockIdx.x * blockDim.x + threadIdx.x;
    if (idx < n) p[idx] = 0;
}

// ---------------------------------------------------------------------------
// pass 1: partition edges into 586 fixed-stride bin arenas (512 rows/bin).
// Per (block, bin): LDS hist -> one global atomicAdd reserves a contiguous
// run in arena[bin*CAP ...]; all stores of a run come from this block -> one
// XCD owns each run -> full-line writebacks. 1024 threads/block for ~19
// waves/CU latency hiding (was 256 thr -> 10.6% occupancy, r11 counters).
// word = val<<32 | col<<9 | row_local9
// ---------------------------------------------------------------------------
__global__ void __launch_bounds__(P1_THREADS)
partition_arena(const int* __restrict__ row,
                const int* __restrict__ col,
                const float* __restrict__ val,
                int* __restrict__ ccur,
                u64* __restrict__ arena) {
    __shared__ int hist[NCOARSE];
    __shared__ int lbase[NCOARSE];
    __shared__ int lcur[NCOARSE];
    int t = threadIdx.x;
    int start = blockIdx.x * P1_CHUNK;
    int end = min(start + P1_CHUNK, NNZ);
    for (int j = t; j < NCOARSE; j += P1_THREADS) { hist[j] = 0; lcur[j] = 0; }
    __syncthreads();
    for (int i = start + t; i < end; i += P1_THREADS)
        atomicAdd(&hist[(unsigned int)row[i] >> COARSE_SHIFT], 1);
    __syncthreads();
    for (int j = t; j < NCOARSE; j += P1_THREADS) {
        int c = hist[j];
        if (c > 0)
            lbase[j] = j * ARENA_CAP + atomicAdd(&ccur[j], c);
    }
    __syncthreads();
    for (int i = start + t; i < end; i += P1_THREADS) {
        int r = row[i];
        int b = (int)((unsigned int)r >> COARSE_SHIFT);
        unsigned int lo = ((unsigned int)col[i] << 9) | ((unsigned int)r & 511u);
        u64 p = ((u64)__float_as_uint(val[i]) << 32) | (u64)lo;
        int pos = lbase[b] + atomicAdd(&lcur[b], 1);
        arena[pos] = p;
    }
}

// ---------------------------------------------------------------------------
// exclusive scan of 586 final bin counts -> cbase[0..586] (cbase[586] = NNZ)
// ---------------------------------------------------------------------------
__global__ void __launch_bounds__(1024)
arena_scan(const int* __restrict__ cnt, int* __restrict__ cbase) {
    __shared__ int lds[1024];
    int t = threadIdx.x;
    lds[t] = (t < NCOARSE) ? cnt[t] : 0;
    __syncthreads();
    for (int off = 1; off < 1024; off <<= 1) {
        int v = (t >= off) ? lds[t - off] : 0;
        __syncthreads();
        lds[t] += v;
        __syncthreads();
    }
    if (t < NCOARSE) cbase[t] = (t > 0) ? lds[t - 1] : 0;
    if (t == 0) cbase[NCOARSE] = lds[NCOARSE - 1];
}

// ---------------------------------------------------------------------------
// pass 2: one block per 512-row bin. Stage the bin's arena region ONCE in
// dynamic LDS, LDS hist by row_local -> block scan -> row_ptr, then scatter
// LDS -> final row-sorted CSR (block-private ~70KB window). Fallback branch:
// global two-pass for (statistically unreachable) n > FS_CAP.
// ---------------------------------------------------------------------------
__global__ void __launch_bounds__(1024)
fine_scatter(const int* __restrict__ cbase,
             const int* __restrict__ cnt,
             const u64* __restrict__ arena,
             u64* __restrict__ csr,
             int* __restrict__ row_ptr) {
    extern __shared__ u64 smem[];
    u64* buf  = smem;
    int* offs = (int*)&smem[FS_CAP];
    int* cur  = offs + COARSE_ROWS;
    int t = threadIdx.x;
    int bin = blockIdx.x;
    int n = cnt[bin];
    int cstart = cbase[bin];
    const u64* src = arena + (size_t)bin * ARENA_CAP;
    if (t < COARSE_ROWS) { offs[t] = 0; cur[t] = 0; }
    __syncthreads();
    if (n <= FS_CAP) {
        for (int i = t; i < n; i += 1024) {
            u64 p = src[i];
            buf[i] = p;
            atomicAdd(&offs[(unsigned int)p & 511u], 1);
        }
        __syncthreads();
        int c = (t < COARSE_ROWS) ? offs[t] : 0;
        for (int off = 1; off < COARSE_ROWS; off <<= 1) {
            int v = (t >= off && t < COARSE_ROWS) ? offs[t - off] : 0;
            __syncthreads();
            if (t < COARSE_ROWS) offs[t] += v;
            __syncthreads();
        }
        int excl = (t < COARSE_ROWS) ? offs[t] - c : 0;
        __syncthreads();
        if (t < COARSE_ROWS) offs[t] = excl;
        __syncthreads();
        int r = (bin << COARSE_SHIFT) + t;
        if (t < COARSE_ROWS && r < N_NODES) row_ptr[r] = cstart + excl;
        if (bin == NCOARSE - 1 && t == 0) row_ptr[N_NODES] = cbase[NCOARSE];
        for (int i = t; i < n; i += 1024) {
            u64 p = buf[i];
            int rl = (int)((unsigned int)p & 511u);
            int pos = cstart + offs[rl] + atomicAdd(&cur[rl], 1);
            csr[pos] = p;
        }
    } else {
        // fallback: global two-pass (same semantics, no LDS staging)
        for (int i = t; i < n; i += 1024)
            atomicAdd(&offs[(unsigned int)src[i] & 511u], 1);
        __syncthreads();
        int c = (t < COARSE_ROWS) ? offs[t] : 0;
        for (int off = 1; off < COARSE_ROWS; off <<= 1) {
            int v = (t >= off && t < COARSE_ROWS) ? offs[t - off] : 0;
            __syncthreads();
            if (t < COARSE_ROWS) offs[t] += v;
            __syncthreads();
        }
        int excl = (t < COARSE_ROWS) ? offs[t] - c : 0;
        __syncthreads();
        if (t < COARSE_ROWS) offs[t] = excl;
        __syncthreads();
        int r = (bin << COARSE_SHIFT) + t;
        if (t < COARSE_ROWS && r < N_NODES) row_ptr[r] = cstart + excl;
        if (bin == NCOARSE - 1 && t == 0) row_ptr[N_NODES] = cbase[NCOARSE];
        for (int i = t; i < n; i += 1024) {
            u64 p = src[i];
            int rl = (int)((unsigned int)p & 511u);
            int pos = cstart + offs[rl] + atomicAdd(&cur[rl], 1);
            csr[pos] = p;
        }
    }
}

// ---------------------------------------------------------------------------
// pair-row gather core: two adjacent rows per wave, joint 8+8 loop
// (16 gathers in flight), then per-row 8/4/1 tails.
// edge word: val<<32 | col<<9 | row_local9  ->  col = low32 >> 9
// ---------------------------------------------------------------------------
__device__ __forceinline__ void tail_accum(const u64* __restrict__ csr,
                                           const __half* __restrict__ x,
                                           int lane, int k, int e, float& acc) {
    for (; k + 8 <= e; k += 8) {
        u64 p0 = csr[k],     p1 = csr[k + 1], p2 = csr[k + 2], p3 = csr[k + 3];
        u64 p4 = csr[k + 4], p5 = csr[k + 5], p6 = csr[k + 6], p7 = csr[k + 7];
        float x0 = __half2float(x[(((unsigned int)p0 >> 9) << 6) + lane]);
        float x1 = __half2float(x[(((unsigned int)p1 >> 9) << 6) + lane]);
        float x2 = __half2float(x[(((unsigned int)p2 >> 9) << 6) + lane]);
        float x3 = __half2float(x[(((unsigned int)p3 >> 9) << 6) + lane]);
        float x4 = __half2float(x[(((unsigned int)p4 >> 9) << 6) + lane]);
        float x5 = __half2float(x[(((unsigned int)p5 >> 9) << 6) + lane]);
        float x6 = __half2float(x[(((unsigned int)p6 >> 9) << 6) + lane]);
        float x7 = __half2float(x[(((unsigned int)p7 >> 9) << 6) + lane]);
        acc += __uint_as_float((unsigned int)(p0 >> 32)) * x0;
        acc += __uint_as_float((unsigned int)(p1 >> 32)) * x1;
        acc += __uint_as_float((unsigned int)(p2 >> 32)) * x2;
        acc += __uint_as_float((unsigned int)(p3 >> 32)) * x3;
        acc += __uint_as_float((unsigned int)(p4 >> 32)) * x4;
        acc += __uint_as_float((unsigned int)(p5 >> 32)) * x5;
        acc += __uint_as_float((unsigned int)(p6 >> 32)) * x6;
        acc += __uint_as_float((unsigned int)(p7 >> 32)) * x7;
    }
    for (; k + 4 <= e; k += 4) {
        u64 p0 = csr[k], p1 = csr[k + 1], p2 = csr[k + 2], p3 = csr[k + 3];
        float x0 = __half2float(x[(((unsigned int)p0 >> 9) << 6) + lane]);
        float x1 = __half2float(x[(((unsigned int)p1 >> 9) << 6) + lane]);
        float x2 = __half2float(x[(((unsigned int)p2 >> 9) << 6) + lane]);
        float x3 = __half2float(x[(((unsigned int)p3 >> 9) << 6) + lane]);
        acc += __uint_as_float((unsigned int)(p0 >> 32)) * x0;
        acc += __uint_as_float((unsigned int)(p1 >> 32)) * x1;
        acc += __uint_as_float((unsigned int)(p2 >> 32)) * x2;
        acc += __uint_as_float((unsigned int)(p3 >> 32)) * x3;
    }
    for (; k < e; ++k) {
        u64 p = csr[k];
        acc += __uint_as_float((unsigned int)(p >> 32))
             * __half2float(x[(((unsigned int)p >> 9) << 6) + lane]);
    }
}

__device__ __forceinline__ void pair_accum(const int* __restrict__ row_ptr,
                                           const u64* __restrict__ csr,
                                           const __half* __restrict__ x,
                                           int lane, int r0,
                                           float& acc0, float& acc1) {
    int s0 = row_ptr[r0];
    int e0 = row_ptr[r0 + 1];
    int e1 = row_ptr[r0 + 2];
    int k0 = s0, k1 = e0;
    while (k0 + 8 <= e0 && k1 + 8 <= e1) {
        u64 p0 = csr[k0],     p1 = csr[k0 + 1], p2 = csr[k0 + 2], p3 = csr[k0 + 3];
        u64 p4 = csr[k0 + 4], p5 = csr[k0 + 5], p6 = csr[k0 + 6], p7 = csr[k0 + 7];
        u64 q0 = csr[k1],     q1 = csr[k1 + 1], q2 = csr[k1 + 2], q3 = csr[k1 + 3];
        u64 q4 = csr[k1 + 4], q5 = csr[k1 + 5], q6 = csr[k1 + 6], q7 = csr[k1 + 7];
        float a0 = __half2float(x[(((unsigned int)p0 >> 9) << 6) + lane]);
        float a1 = __half2float(x[(((unsigned int)p1 >> 9) << 6) + lane]);
        float a2 = __half2float(x[(((unsigned int)p2 >> 9) << 6) + lane]);
        float a3 = __half2float(x[(((unsigned int)p3 >> 9) << 6) + lane]);
        float a4 = __half2float(x[(((unsigned int)p4 >> 9) << 6) + lane]);
        float a5 = __half2float(x[(((unsigned int)p5 >> 9) << 6) + lane]);
        float a6 = __half2float(x[(((unsigned int)p6 >> 9) << 6) + lane]);
        float a7 = __half2float(x[(((unsigned int)p7 >> 9) << 6) + lane]);
        float b0 = __half2float(x[(((unsigned int)q0 >> 9) << 6) + lane]);
        float b1 = __half2float(x[(((unsigned int)q1 >> 9) << 6) + lane]);
        float b2 = __half2float(x[(((unsigned int)q2 >> 9) << 6) + lane]);
        float b3 = __half2float(x[(((unsigned int)q3 >> 9) << 6) + lane]);
        float b4 = __half2float(x[(((unsigned int)q4 >> 9) << 6) + lane]);
        float b5 = __half2float(x[(((unsigned int)q5 >> 9) << 6) + lane]);
        float b6 = __half2float(x[(((unsigned int)q6 >> 9) << 6) + lane]);
        float b7 = __half2float(x[(((unsigned int)q7 >> 9) << 6) + lane]);
        acc0 += __uint_as_float((unsigned int)(p0 >> 32)) * a0;
        acc0 += __uint_as_float((unsigned int)(p1 >> 32)) * a1;
        acc0 += __uint_as_float((unsigned int)(p2 >> 32)) * a2;
        acc0 += __uint_as_float((unsigned int)(p3 >> 32)) * a3;
        acc0 += __uint_as_float((unsigned int)(p4 >> 32)) * a4;
        acc0 += __uint_as_float((unsigned int)(p5 >> 32)) * a5;
        acc0 += __uint_as_float((unsigned int)(p6 >> 32)) * a6;
        acc0 += __uint_as_float((unsigned int)(p7 >> 32)) * a7;
        acc1 += __uint_as_float((unsigned int)(q0 >> 32)) * b0;
        acc1 += __uint_as_float((unsigned int)(q1 >> 32)) * b1;
        acc1 += __uint_as_float((unsigned int)(q2 >> 32)) * b2;
        acc1 += __uint_as_float((unsigned int)(q3 >> 32)) * b3;
        acc1 += __uint_as_float((unsigned int)(q4 >> 32)) * b4;
        acc1 += __uint_as_float((unsigned int)(q5 >> 32)) * b5;
        acc1 += __uint_as_float((unsigned int)(q6 >> 32)) * b6;
        acc1 += __uint_as_float((unsigned int)(q7 >> 32)) * b7;
        k0 += 8; k1 += 8;
    }
    tail_accum(csr, x, lane, k0, e0, acc0);
    tail_accum(csr, x, lane, k1, e1, acc1);
}

// ---------------------------------------------------------------------------
// pull SpMM mid-layer: two rows per wave, lane = dim. Writes y only.
// ---------------------------------------------------------------------------
__global__ void spmm_mid_kernel(const int* __restrict__ row_ptr,
                                const u64* __restrict__ csr,
                                const __half* __restrict__ x,
                                __half* __restrict__ y) {
    int gid  = blockIdx.x * blockDim.x + threadIdx.x;
    int r0   = (gid >> 6) * 2;
    int lane = threadIdx.x & 63;
    if (r0 >= N_NODES) return;
    r0 = __builtin_amdgcn_readfirstlane(r0);  // force SGPR: scalar edge loads
    float acc0 = 0.f, acc1 = 0.f;
    pair_accum(row_ptr, csr, x, lane, r0, acc0, acc1);
    int o = (r0 << 6) + lane;
    y[o]      = __float2half(acc0);
    y[o + 64] = __float2half(acc1);
}

// ---------------------------------------------------------------------------
// pull SpMM last layer, fused combine (two rows per wave):
// out = (h0(emb fp32) + h1 + h2 + A*h2) * 0.25, single NT write, no y.
// ---------------------------------------------------------------------------
__global__ void spmm_last_kernel(const int* __restrict__ row_ptr,
                                 const u64* __restrict__ csr,
                                 const __half* __restrict__ x,    // h2
                                 const __half* __restrict__ h1,
                                 const float* __restrict__ user_emb,
                                 const float* __restrict__ item_emb,
                                 float* __restrict__ out) {
    int gid  = blockIdx.x * blockDim.x + threadIdx.x;
    int r0   = (gid >> 6) * 2;
    int lane = threadIdx.x & 63;
    if (r0 >= N_NODES) return;
    r0 = __builtin_amdgcn_readfirstlane(r0);  // force SGPR: scalar edge loads
    float acc0 = 0.f, acc1 = 0.f;
    pair_accum(row_ptr, csr, x, lane, r0, acc0, acc1);
    int o0 = (r0 << 6) + lane;
    int o1 = o0 + 64;
    float h00 = (o0 < NUM_USERS * EMB_DIM) ? user_emb[o0]
                                           : item_emb[o0 - NUM_USERS * EMB_DIM];
    float h01 = (o1 < NUM_USERS * EMB_DIM) ? user_emb[o1]
                                           : item_emb[o1 - NUM_USERS * EMB_DIM];
    float r0v = (h00 + __half2float(h1[o0]) + __half2float(x[o0]) + acc0) * 0.25f;
    float r1v = (h01 + __half2float(h1[o1]) + __half2float(x[o1]) + acc1) * 0.25f;
    __builtin_nontemporal_store(r0v, &out[o0]);
    __builtin_nontemporal_store(r1v, &out[o1]);
}

// ---------------------------------------------------------------------------
// fallback (round-1 push path) if ws too small
// ---------------------------------------------------------------------------
__global__ void init32_kernel(const float4* __restrict__ user_emb,
                              const float4* __restrict__ item_emb,
                              float4* __restrict__ h,
                              float4* __restrict__ out) {
    const int n4 = N_NODES * (EMB_DIM / 4);
    int idx = blockIdx.x * blockDim.x + threadIdx.x;
    if (idx >= n4) return;
    const int user4 = NUM_USERS * (EMB_DIM / 4);
    float4 v = (idx < user4) ? user_emb[idx] : item_emb[idx - user4];
    h[idx] = v;
    out[idx] = v;
}
__global__ void zero4_kernel(float4* __restrict__ p) {
    const int n4 = N_NODES * (EMB_DIM / 4);
    int idx = blockIdx.x * blockDim.x + threadIdx.x;
    if (idx < n4) p[idx] = make_float4(0.f, 0.f, 0.f, 0.f);
}
__global__ void spmm_push_kernel(const int* __restrict__ row, const int* __restrict__ col,
                                 const float* __restrict__ val, const float* __restrict__ x,
                                 float* __restrict__ y) {
    unsigned int gid = blockIdx.x * blockDim.x + threadIdx.x;
    unsigned int e = gid >> 6, lane = gid & 63u;
    if (e >= NNZ) return;
    atomicAdd(&y[(unsigned int)row[e] * EMB_DIM + lane],
              val[e] * x[(unsigned int)col[e] * EMB_DIM + lane]);
}
__global__ void acc_kernel(float4* __restrict__ out, const float4* __restrict__ h, float scale) {
    const int n4 = N_NODES * (EMB_DIM / 4);
    int idx = blockIdx.x * blockDim.x + threadIdx.x;
    if (idx >= n4) return;
    float4 o = out[idx], a = h[idx];
    o.x = (o.x + a.x) * scale; o.y = (o.y + a.y) * scale;
    o.z = (o.z + a.z) * scale; o.w = (o.w + a.w) * scale;
    out[idx] = o;
}

extern "C" void kernel_launch(void* const* d_in, const int* in_sizes, int n_in,
                              void* d_out, int out_size, void* d_ws, size_t ws_size,
                              hipStream_t stream) {
    const float* user_emb = (const float*)d_in[0];
    const float* item_emb = (const float*)d_in[1];
    const int*   edge_row = (const int*)d_in[2];
    const int*   edge_col = (const int*)d_in[3];
    const float* edge_val = (const float*)d_in[4];
    float* out = (float*)d_out;

    const size_t H16_BYTES = (size_t)N_NODES * EMB_DIM * sizeof(__half);  // 38.4 MB

    char* ws = (char*)d_ws;
    __half* hA     = (__half*)ws;                      ws += H16_BYTES;
    __half* hB     = (__half*)ws;                      ws += H16_BYTES;
    u64*    csr    = (u64*)ws;                         ws += (size_t)NNZ * 8;
    int*   row_ptr = (int*)ws;                         ws += (size_t)(N_NODES + 4) * 4;
    int*   counts  = (int*)ws;                         ws += (size_t)N_NODES * 4;
    int*   partials= (int*)ws;                         ws += 4096;
    const size_t REQUIRED = (size_t)(ws - (char*)d_ws);

    const int blk     = 256;
    const int n4      = N_NODES * (EMB_DIM / 4);
    const int grid_n4 = (n4 + blk - 1) / blk;

    if (ws_size >= REQUIRED) {
        // ---- build packed, row-sorted CSR (arena partition + fine scatter) ----
        // counts[0..NCOARSE): bin cursors/counts; partials: cbase[0..NCOARSE]
        // arena reuses hA/hB region (57.6 MB <= 76.8 MB), dead before init.
        u64* arena = (u64*)hA;
        zero_int_kernel<<<1, 1024, 0, stream>>>(counts, NCOARSE);
        partition_arena<<<P1_BLOCKS, P1_THREADS, 0, stream>>>(
            edge_row, edge_col, edge_val, counts, arena);
        arena_scan<<<1, 1024, 0, stream>>>(counts, partials);
        fine_scatter<<<NCOARSE, 1024, FS_SHMEM, stream>>>(partials, counts, arena,
                                                          csr, row_ptr);
        // ---- propagate: h0 -> h1 -> h2 -> fused final combine ----
        init16_kernel<<<grid_n4, blk, 0, stream>>>(
            (const float4*)user_emb, (const float4*)item_emb, (uint2*)hA);
        const int grid_sp = (int)(((long long)(N_NODES / 2) * 64) / blk);  // 37,500
        spmm_mid_kernel<<<grid_sp, blk, 0, stream>>>(row_ptr, csr, hA, hB); // h1
        spmm_mid_kernel<<<grid_sp, blk, 0, stream>>>(row_ptr, csr, hB, hA); // h2 (over h0)
        spmm_last_kernel<<<grid_sp, blk, 0, stream>>>(
            row_ptr, csr, hA /*h2*/, hB /*h1*/, user_emb, item_emb, out);
    } else {
        // fallback: fp32 push path (needs only 2 * 76.8 MB)
        const float scales[3] = {1.0f, 1.0f, 0.25f};
        float* hA32 = (float*)d_ws;
        float* hB32 = hA32 + (size_t)N_NODES * EMB_DIM;
        init32_kernel<<<grid_n4, blk, 0, stream>>>(
            (const float4*)user_emb, (const float4*)item_emb, (float4*)hA32, (float4*)out);
        float* h = hA32; float* hn = hB32;
        const int grid_sp = (int)(((long long)NNZ * 64) / blk);
        for (int layer = 0; layer < 3; ++layer) {
            zero4_kernel<<<grid_n4, blk, 0, stream>>>((float4*)hn);
            spmm_push_kernel<<<grid_sp, blk, 0, stream>>>(edge_row, edge_col, edge_val, h, hn);
            acc_kernel<<<grid_n4, blk, 0, stream>>>((float4*)out, (const float4*)hn, scales[layer]);
            float* t = h; h = hn; hn = t;
        }
    }
}